// Round 10
// baseline (223.379 us; speedup 1.0000x reference)
//
#include <hip/hip_runtime.h>
#include <hip/hip_bf16.h>

typedef __hip_bfloat16 bf16;
typedef __attribute__((ext_vector_type(8))) short bf16x8;   // 8 bf16 (4 VGPRs)
typedef __attribute__((ext_vector_type(4))) float f32x4;

#define T_LEN 2048
#define DMODEL 1024
#define DINNER 2048
#define DSTATE 16
#define LN_EPS 1e-5f
#define NCHUNK 128
#define CLEN 16     // NCHUNK * CLEN == T_LEN
#define SSTR 64     // ssm row stride (36 used, padded to 64)
#define PSEG 131072 // elems per split-K partial (2048*64)
#define KSPLIT 4    // gemm2 split-K slices

#define GLOBAL_AS __attribute__((address_space(1)))
#define LDS_AS __attribute__((address_space(3)))

__device__ __forceinline__ void g2l16(void* lds, const void* g) {
    __builtin_amdgcn_global_load_lds((const GLOBAL_AS void*)g, (LDS_AS void*)lds, 16, 0, 0);
}

__device__ __forceinline__ float b2f(short s) {
    return __uint_as_float(((unsigned)(unsigned short)s) << 16);
}

__device__ __forceinline__ unsigned short f2bu(float f) {
    bf16 b = __float2bfloat16(f);
    return *reinterpret_cast<unsigned short*>(&b);
}

// buf element j of a row held as f32x4 vectors; j must be compile-time const
#define BG(buf, j) (buf[(j) >> 2][(j) & 3])

// ---------- weight preps + LayerNorm in ONE launch ----------
// W_x column remap so ssm rows are: col 0 = dt_raw, cols 4..19 = B, cols 20..35 = C.
__global__ void prep_all(const float* __restrict__ Win, const float* __restrict__ Wout,
                         const float* __restrict__ Wx, const float* __restrict__ x,
                         const float* __restrict__ lng, const float* __restrict__ lnb,
                         bf16* __restrict__ WinT, bf16* __restrict__ WoutT,
                         bf16* __restrict__ WxT, bf16* __restrict__ xn) {
    __shared__ float t[32][33];
    int bid = blockIdx.x, tid = threadIdx.x;
    int tx = tid & 31, ty4 = (tid >> 5) * 4;
    if (bid < 4096) {               // W_in [1024][4096] -> WinT [4096][1024]
        int n0 = (bid & 127) * 32, k0 = (bid >> 7) * 32;
#pragma unroll
        for (int r = 0; r < 4; r++)
            t[ty4 + r][tx] = Win[(size_t)(k0 + ty4 + r) * 4096 + n0 + tx];
        __syncthreads();
#pragma unroll
        for (int r = 0; r < 4; r++)
            WinT[(size_t)(n0 + ty4 + r) * 1024 + k0 + tx] = __float2bfloat16(t[tx][ty4 + r]);
    } else if (bid < 6144) {        // W_out [2048][1024] -> WoutT [1024][2048]
        int b = bid - 4096;
        int n0 = (b & 31) * 32, k0 = (b >> 5) * 32;
#pragma unroll
        for (int r = 0; r < 4; r++)
            t[ty4 + r][tx] = Wout[(size_t)(k0 + ty4 + r) * 1024 + n0 + tx];
        __syncthreads();
#pragma unroll
        for (int r = 0; r < 4; r++)
            WoutT[(size_t)(n0 + ty4 + r) * 2048 + k0 + tx] = __float2bfloat16(t[tx][ty4 + r]);
    } else if (bid < 6656) {        // W_x [2048][33] -> WxT [64][2048], remapped + zero-pad
        int idx = (bid - 6144) * 256 + tid;
        int n = idx >> 11, k = idx & 2047;
        int j = (n == 0) ? 0 : (n >= 4 && n <= 35) ? n - 3 : -1;
        WxT[idx] = __float2bfloat16(j >= 0 ? Wx[k * 33 + j] : 0.f);
    } else {                        // LayerNorm row
        int row = bid - 6656;
        const float* xr = x + (size_t)row * DMODEL;
        float v[4];
        float s = 0.f, q = 0.f;
#pragma unroll
        for (int i = 0; i < 4; i++) {
            v[i] = xr[tid + i * 256];
            s += v[i];
            q += v[i] * v[i];
        }
        __shared__ float sh_s[256], sh_q[256];
        sh_s[tid] = s; sh_q[tid] = q;
        __syncthreads();
        for (int st = 128; st > 0; st >>= 1) {
            if (tid < st) { sh_s[tid] += sh_s[tid + st]; sh_q[tid] += sh_q[tid + st]; }
            __syncthreads();
        }
        float mean = sh_s[0] * (1.f / DMODEL);
        float var  = sh_q[0] * (1.f / DMODEL) - mean * mean;
        float rstd = rsqrtf(var + LN_EPS);
#pragma unroll
        for (int i = 0; i < 4; i++) {
            int c = tid + i * 256;
            xn[(size_t)row * DMODEL + c] =
                __float2bfloat16((v[i] - mean) * rstd * lng[c] + lnb[c]);
        }
    }
}

// ---------- MFMA GEMM: C = A[M][lda](bf16) * Bt[N][lda](bf16)^T ----------
template <int BM, int BN, int WAVE_M, int WAVE_N, int WRITE_RESID, int OUT_BF16>
__global__ void gemm_mfma(const bf16* __restrict__ A, const bf16* __restrict__ Bt,
                          void* __restrict__ Cv, const float* __restrict__ resid,
                          int M, int N, int Kslice, int lda) {
    constexpr int WMsz = BM / WAVE_M;
    constexpr int WNsz = BN / WAVE_N;
    constexpr int TM = WMsz / 16;
    constexpr int TN = WNsz / 16;
    __shared__ short As[BM * 64];
    __shared__ short Bs[BN * 64];
    int tid = threadIdx.x;
    int lane = tid & 63, wave = tid >> 6;
    int wm = (wave / WAVE_N) * WMsz, wn = (wave % WAVE_N) * WNsz;
    int rowBase = blockIdx.y * BM, colBase = blockIdx.x * BN;
    int kbase = blockIdx.z * Kslice;

    f32x4 acc[TM][TN];
#pragma unroll
    for (int i = 0; i < TM; i++)
#pragma unroll
        for (int j = 0; j < TN; j++) acc[i][j] = f32x4{0.f, 0.f, 0.f, 0.f};

    int srow = tid >> 3;
    int cc = (tid & 7) ^ (srow & 7);
    const int ldsoff = tid * 16;

    for (int k0 = kbase; k0 < kbase + Kslice; k0 += 64) {
#pragma unroll
        for (int j = 0; j < BM / 32; j++)
            g2l16((char*)As + j * 4096 + ldsoff,
                  A + (size_t)(rowBase + j * 32 + srow) * lda + k0 + cc * 8);
#pragma unroll
        for (int j = 0; j < BN / 32; j++)
            g2l16((char*)Bs + j * 4096 + ldsoff,
                  Bt + (size_t)(colBase + j * 32 + srow) * lda + k0 + cc * 8);
        __syncthreads();
#pragma unroll
        for (int ks = 0; ks < 2; ks++) {
            bf16x8 af[TM], bfr[TN];
#pragma unroll
            for (int i = 0; i < TM; i++) {
                int row = wm + i * 16 + (lane & 15);
                int slot = (ks * 4 + (lane >> 4)) ^ (row & 7);
                af[i] = *(const bf16x8*)((const char*)As + row * 128 + slot * 16);
            }
#pragma unroll
            for (int j = 0; j < TN; j++) {
                int row = wn + j * 16 + (lane & 15);
                int slot = (ks * 4 + (lane >> 4)) ^ (row & 7);
                bfr[j] = *(const bf16x8*)((const char*)Bs + row * 128 + slot * 16);
            }
#pragma unroll
            for (int i = 0; i < TM; i++)
#pragma unroll
                for (int j = 0; j < TN; j++)
                    acc[i][j] = __builtin_amdgcn_mfma_f32_16x16x32_bf16(
                        af[i], bfr[j], acc[i][j], 0, 0, 0);
        }
        __syncthreads();
    }
    int rq = lane >> 4, cn = lane & 15;
    float* Cf = (float*)Cv + (size_t)blockIdx.z * M * N;
#pragma unroll
    for (int i = 0; i < TM; i++) {
#pragma unroll
        for (int j = 0; j < TN; j++) {
#pragma unroll
            for (int r = 0; r < 4; r++) {
                size_t row = rowBase + wm + i * 16 + rq * 4 + r;
                int col = colBase + wn + j * 16 + cn;
                float v = acc[i][j][r];
                if (WRITE_RESID) v += resid[row * N + col];
                if (OUT_BF16)
                    ((bf16*)Cv)[row * N + col] = __float2bfloat16(v);
                else
                    Cf[row * N + col] = v;
            }
        }
    }
}

// ---------- Causal depthwise conv(4) + SiLU, 4-wide over d ----------
__global__ void conv_silu(const bf16* __restrict__ xz, const float* __restrict__ cw,
                          const float* __restrict__ cb, bf16* __restrict__ xc) {
    int idx = blockIdx.x * 256 + threadIdx.x;   // T_LEN * DINNER/4 threads
    int t = idx >> 9, d4 = (idx & 511) * 4;
    const f32x4 bv = *(const f32x4*)(cb + d4);
    float acc0 = bv[0], acc1 = bv[1], acc2 = bv[2], acc3 = bv[3];
    const f32x4* cwv = (const f32x4*)(cw + d4 * 4);  // rows d4..d4+3
    f32x4 w0 = cwv[0], w1 = cwv[1], w2 = cwv[2], w3 = cwv[3];
#pragma unroll
    for (int k = 0; k < 4; k++) {
        int tt = t - 3 + k;
        if (tt >= 0) {
            ushort4 v = *(const ushort4*)((const short*)xz + (size_t)tt * (2 * DINNER) + d4);
            acc0 = fmaf(b2f((short)v.x), w0[k], acc0);
            acc1 = fmaf(b2f((short)v.y), w1[k], acc1);
            acc2 = fmaf(b2f((short)v.z), w2[k], acc2);
            acc3 = fmaf(b2f((short)v.w), w3[k], acc3);
        }
    }
    ushort4 o;
    o.x = f2bu(acc0 / (1.f + __expf(-acc0)));
    o.y = f2bu(acc1 / (1.f + __expf(-acc1)));
    o.z = f2bu(acc2 / (1.f + __expf(-acc2)));
    o.w = f2bu(acc3 / (1.f + __expf(-acc3)));
    *(ushort4*)((short*)xc + (size_t)t * DINNER + d4) = o;
}

// ---------- sum the KSPLIT split-K partials once: ssm[t][64] ----------
__global__ void reduce_parts(const float* __restrict__ parts, float* __restrict__ ssm) {
    int idx = (blockIdx.x * 256 + threadIdx.x) * 4;
    f32x4 s = f32x4{0.f, 0.f, 0.f, 0.f};
#pragma unroll
    for (int k = 0; k < KSPLIT; k++)
        s += *(const f32x4*)(parts + idx + (size_t)k * PSEG);
    *(f32x4*)(ssm + idx) = s;
}

__device__ __forceinline__ float softplus_f(float pre) {
    return (pre > 20.f) ? pre : log1pf(__expf(pre));
}

// q^1..q^16 in a[0..15], log-depth
__device__ __forceinline__ void powtree(float q, float* a) {
    a[0] = q;
    a[1] = q * q;
    a[2] = a[1] * q;
    a[3] = a[1] * a[1];
#pragma unroll
    for (int j = 0; j < 4; j++) a[4 + j] = a[j] * a[3];
#pragma unroll
    for (int j = 0; j < 8; j++) a[8 + j] = a[j] * a[7];
}

__device__ __forceinline__ void ldrow9(f32x4* b, const f32x4* sp) {
#pragma unroll
    for (int k = 0; k < 9; k++) b[k] = sp[k];
}

// ---------- Scan pass 1: chunk-local scan, emits S (chunk-end h_local),
// y_local = C·h_local per step, and inclusive dt-prefix Lt ----------
__global__ void scan_pass1(
        const float* __restrict__ ssm, const bf16* __restrict__ xc,
        const float* __restrict__ Wdt, const float* __restrict__ bdt,
        const float* __restrict__ Alog,
        float* __restrict__ Ld, float* __restrict__ S,
        float* __restrict__ Lt, float* __restrict__ yloc) {
    int tid = threadIdx.x;
    int d = blockIdx.x * 256 + tid;
    int c = blockIdx.y;
    int t0 = c * CLEN;
    float A[DSTATE];
    bool fast = true;
#pragma unroll
    for (int n = 0; n < DSTATE; n++) {
        A[n] = -__expf(Alog[d * DSTATE + n]);
        fast = fast && (fabsf(A[n] + (float)(n + 1)) < 1e-3f * (n + 1));
    }
    float wdt = Wdt[d], bd = bdt[d];
    float Sv[DSTATE];
#pragma unroll
    for (int n = 0; n < DSTATE; n++) Sv[n] = 0.f;
    float Lsum = 0.f;
    const f32x4* sp = (const f32x4*)(ssm + (size_t)t0 * SSTR);
    const short* xcp = (const short*)xc + (size_t)t0 * DINNER + d;
    short xcv[CLEN];
#pragma unroll
    for (int i = 0; i < CLEN; i++)
        xcv[i] = xcp[(size_t)i * DINNER];
    float* Ltp = Lt + (size_t)t0 * DINNER + d;
    float* ylp = yloc + (size_t)t0 * DINNER + d;
    if (fast) {
#pragma unroll
        for (int i = 0; i < CLEN; i++) {
            f32x4 buf[9];
            ldrow9(buf, sp + i * 16);
            float dt = softplus_f(BG(buf, 0) * wdt + bd);
            Lsum += dt;
            float u = dt * b2f(xcv[i]);
            float a[DSTATE];
            powtree(__expf(-dt), a);
            float y0 = 0.f, y1 = 0.f, y2 = 0.f, y3 = 0.f;
#pragma unroll
            for (int n = 0; n < 4; n++) {
                Sv[n]      = fmaf(a[n],      Sv[n],      u * BG(buf, 4 + n));
                y0 = fmaf(Sv[n],      BG(buf, 20 + n), y0);
                Sv[n + 4]  = fmaf(a[n + 4],  Sv[n + 4],  u * BG(buf, 8 + n));
                y1 = fmaf(Sv[n + 4],  BG(buf, 24 + n), y1);
                Sv[n + 8]  = fmaf(a[n + 8],  Sv[n + 8],  u * BG(buf, 12 + n));
                y2 = fmaf(Sv[n + 8],  BG(buf, 28 + n), y2);
                Sv[n + 12] = fmaf(a[n + 12], Sv[n + 12], u * BG(buf, 16 + n));
                y3 = fmaf(Sv[n + 12], BG(buf, 32 + n), y3);
            }
            Ltp[(size_t)i * DINNER] = Lsum;
            ylp[(size_t)i * DINNER] = (y0 + y1) + (y2 + y3);
        }
    } else {
#pragma unroll
        for (int i = 0; i < CLEN; i++) {
            f32x4 buf[9];
            ldrow9(buf, sp + i * 16);
            float dt = softplus_f(BG(buf, 0) * wdt + bd);
            Lsum += dt;
            float u = dt * b2f(xcv[i]);
            float y = 0.f;
#pragma unroll
            for (int n = 0; n < DSTATE; n++) {
                float a = __expf(dt * A[n]);
                Sv[n] = fmaf(a, Sv[n], u * BG(buf, 4 + n));
                y = fmaf(Sv[n], BG(buf, 20 + n), y);
            }
            Ltp[(size_t)i * DINNER] = Lsum;
            ylp[(size_t)i * DINNER] = y;
        }
    }
    Ld[(size_t)c * DINNER + d] = Lsum;
    size_t base = (size_t)c * DINNER * DSTATE + d;   // [c][n][d]
#pragma unroll
    for (int n = 0; n < DSTATE; n++)
        S[base + (size_t)n * DINNER] = Sv[n];
}

// ---------- Scan pass 2: block-segmented scan over chunks ----------
// grid (DINNER/64, DSTATE), 256 thr = 64 d x 4 segments of 32 chunks.
#define SEGL (NCHUNK / 4)
__global__ void scan_pass2(const float* __restrict__ Ld, const float* __restrict__ S,
                           const float* __restrict__ Alog, float* __restrict__ Hst) {
    int tx = threadIdx.x & 63, ty = threadIdx.x >> 6;
    int d = blockIdx.x * 64 + tx;
    int n = blockIdx.y;
    float A = -__expf(Alog[d * DSTATE + n]);
    int c0 = ty * SEGL;
    float lv[SEGL], sv[SEGL];
#pragma unroll
    for (int j = 0; j < SEGL; j++) {
        int cc = c0 + j;
        lv[j] = Ld[(size_t)cc * DINNER + d];
        sv[j] = S[(size_t)cc * DINNER * DSTATE + (size_t)n * DINNER + d];
    }
    float Lsum = 0.f, Sseg = 0.f;
#pragma unroll
    for (int j = 0; j < SEGL; j++) {
        Sseg = fmaf(__expf(A * lv[j]), Sseg, sv[j]);
        Lsum += lv[j];
    }
    __shared__ float shL[4][64], shS[4][64], shC[4][64];
    shL[ty][tx] = Lsum;
    shS[ty][tx] = Sseg;
    __syncthreads();
    if (ty == 0) {
        float car = 0.f;
        shC[0][tx] = 0.f;
#pragma unroll
        for (int s = 0; s < 3; s++) {
            car = fmaf(__expf(A * shL[s][tx]), car, shS[s][tx]);
            shC[s + 1][tx] = car;
        }
    }
    __syncthreads();
    float H = shC[ty][tx];
#pragma unroll
    for (int j = 0; j < SEGL; j++) {
        size_t o = (size_t)(c0 + j) * DINNER * DSTATE + (size_t)n * DINNER + d;
        Hst[o] = H;
        H = fmaf(__expf(A * lv[j]), H, sv[j]);
    }
}

// ---------- Scan pass 3: FULLY PARALLEL correction + fused epilogue ----------
// y_t = y_local_t + sum_n C_t[n] * exp(A[n]*Lt_t) * H_start[n]; no recurrence.
__global__ void scan_pass3(
        const float* __restrict__ ssm, const float* __restrict__ Lt,
        const float* __restrict__ yloc,
        const bf16* __restrict__ xc, const bf16* __restrict__ xz,
        const float* __restrict__ Alog, const float* __restrict__ Dp,
        const float* __restrict__ Hst, bf16* __restrict__ yf) {
    int tid = threadIdx.x;
    int d = blockIdx.x * 256 + tid;
    int c = blockIdx.y;
    int t0 = c * CLEN;
    float A[DSTATE], H[DSTATE];
    bool fast = true;
    size_t base = (size_t)c * DINNER * DSTATE + d;
#pragma unroll
    for (int n = 0; n < DSTATE; n++) {
        A[n] = -__expf(Alog[d * DSTATE + n]);
        fast = fast && (fabsf(A[n] + (float)(n + 1)) < 1e-3f * (n + 1));
        H[n] = Hst[base + (size_t)n * DINNER];
    }
    float Dd = Dp[d];
    const float* Ltp = Lt + (size_t)t0 * DINNER + d;
    const float* ylp = yloc + (size_t)t0 * DINNER + d;
    const short* xcp = (const short*)xc + (size_t)t0 * DINNER + d;
    const short* zp  = (const short*)xz + (size_t)t0 * (2 * DINNER) + DINNER + d;
    bf16* yp = yf + (size_t)t0 * DINNER + d;
    float Ltv[CLEN], ylv[CLEN];
    short xcv[CLEN], zv[CLEN];
#pragma unroll
    for (int i = 0; i < CLEN; i++) {
        Ltv[i] = Ltp[(size_t)i * DINNER];
        ylv[i] = ylp[(size_t)i * DINNER];
        xcv[i] = xcp[(size_t)i * DINNER];
        zv[i]  = zp[(size_t)i * 2 * DINNER];
    }
    if (fast) {
        float qv[CLEN];
#pragma unroll
        for (int i = 0; i < CLEN; i++)
            qv[i] = __expf(-Ltv[i]);
#pragma unroll
        for (int i = 0; i < CLEN; i++) {
            const f32x4* cp = (const f32x4*)(ssm + (size_t)(t0 + i) * SSTR) + 5;
            f32x4 cb[4];
#pragma unroll
            for (int k = 0; k < 4; k++) cb[k] = cp[k];
            float a[DSTATE];
            powtree(qv[i], a);
            float y0 = 0.f, y1 = 0.f, y2 = 0.f, y3 = 0.f;
#pragma unroll
            for (int n = 0; n < 4; n++) {
                y0 = fmaf(cb[0][n] * a[n],      H[n],      y0);
                y1 = fmaf(cb[1][n] * a[n + 4],  H[n + 4],  y1);
                y2 = fmaf(cb[2][n] * a[n + 8],  H[n + 8],  y2);
                y3 = fmaf(cb[3][n] * a[n + 12], H[n + 12], y3);
            }
            float xcf = b2f(xcv[i]);
            float y = ylv[i] + (y0 + y1) + (y2 + y3);
            float z = b2f(zv[i]);
            float sz = z / (1.f + __expf(-z));
            yp[(size_t)i * DINNER] = __float2bfloat16(fmaf(xcf, Dd, y) * sz);
        }
    } else {
#pragma unroll
        for (int i = 0; i < CLEN; i++) {
            const f32x4* cp = (const f32x4*)(ssm + (size_t)(t0 + i) * SSTR) + 5;
            f32x4 cb[4];
#pragma unroll
            for (int k = 0; k < 4; k++) cb[k] = cp[k];
            float corr = 0.f;
#pragma unroll
            for (int n = 0; n < DSTATE; n++)
                corr = fmaf(cb[n >> 2][n & 3] * __expf(A[n] * Ltv[i]), H[n], corr);
            float xcf = b2f(xcv[i]);
            float y = ylv[i] + corr;
            float z = b2f(zv[i]);
            float sz = z / (1.f + __expf(-z));
            yp[(size_t)i * DINNER] = __float2bfloat16(fmaf(xcf, Dd, y) * sz);
        }
    }
}

extern "C" void kernel_launch(void* const* d_in, const int* in_sizes, int n_in,
                              void* d_out, int out_size, void* d_ws, size_t ws_size,
                              hipStream_t stream) {
    const float* x     = (const float*)d_in[0];
    const float* W_in  = (const float*)d_in[1];
    const float* convw = (const float*)d_in[2];
    const float* convb = (const float*)d_in[3];
    const float* W_x   = (const float*)d_in[4];
    const float* W_dt  = (const float*)d_in[5];
    const float* b_dt  = (const float*)d_in[6];
    const float* A_log = (const float*)d_in[7];
    const float* Dp    = (const float*)d_in[8];
    const float* W_out = (const float*)d_in[9];
    const float* ln_g  = (const float*)d_in[10];
    const float* ln_b  = (const float*)d_in[11];
    float* out = (float*)d_out;

    // ~120 MB of the 256 MiB workspace; no aliasing.
    char* wsb = (char*)d_ws;
    bf16*  xn    = (bf16*)(wsb);                    //  4 MB
    bf16*  WinT  = (bf16*)(wsb + (4ull  << 20));    //  8 MB
    bf16*  WoutT = (bf16*)(wsb + (12ull << 20));    //  4 MB
    bf16*  WxT   = (bf16*)(wsb + (16ull << 20));    //  0.25 MB
    bf16*  xz    = (bf16*)(wsb + (17ull << 20));    // 16 MB
    bf16*  xc    = (bf16*)(wsb + (33ull << 20));    //  8 MB
    float* parts = (float*)(wsb + (41ull << 20));   //  2 MB (4 x 2048x64)
    float* Ld    = (float*)(wsb + (43ull << 20));   //  1 MB (128 x 2048)
    float* Hst   = (float*)(wsb + (44ull << 20));   // 16 MB
    float* S     = (float*)(wsb + (60ull << 20));   // 16 MB
    bf16*  yf    = (bf16*)(wsb + (76ull << 20));    //  8 MB
    float* ssm   = (float*)(wsb + (84ull << 20));   //  0.5 MB
    float* Lt    = (float*)(wsb + (88ull << 20));   // 16 MB (2048 x 2048 f32)
    float* yloc  = (float*)(wsb + (104ull << 20));  // 16 MB (2048 x 2048 f32)

    prep_all<<<8704, 256, 0, stream>>>(W_in, W_out, W_x, x, ln_g, ln_b,
                                       WinT, WoutT, WxT, xn);

    gemm_mfma<128, 128, 2, 2, 0, 1><<<dim3(4096 / 128, 2048 / 128), 256, 0, stream>>>(
        xn, WinT, xz, nullptr, 2048, 4096, 1024, 1024);

    conv_silu<<<(T_LEN * DINNER / 4) / 256, 256, 0, stream>>>(xz, convw, convb, xc);

    gemm_mfma<32, 64, 2, 2, 0, 0><<<dim3(1, 2048 / 32, KSPLIT), 256, 0, stream>>>(
        xc, WxT, parts, nullptr, 2048, 64, 2048 / KSPLIT, 2048);

    reduce_parts<<<(T_LEN * SSTR / 4) / 256, 256, 0, stream>>>(parts, ssm);

    scan_pass1<<<dim3(DINNER / 256, NCHUNK), 256, 0, stream>>>(
        ssm, xc, W_dt, b_dt, A_log, Ld, S, Lt, yloc);
    scan_pass2<<<dim3(DINNER / 64, DSTATE), 256, 0, stream>>>(Ld, S, A_log, Hst);
    scan_pass3<<<dim3(DINNER / 256, NCHUNK), 256, 0, stream>>>(
        ssm, Lt, yloc, xc, xz, A_log, Dp, Hst, yf);

    gemm_mfma<64, 64, 2, 2, 1, 0><<<dim3(1024 / 64, 2048 / 64), 256, 0, stream>>>(
        yf, WoutT, out, x, 2048, 1024, 2048, 2048);
}

// Round 11
// 221.466 us; speedup vs baseline: 1.0086x; 1.0086x over previous
//
#include <hip/hip_runtime.h>
#include <hip/hip_bf16.h>

typedef __hip_bfloat16 bf16;
typedef __attribute__((ext_vector_type(8))) short bf16x8;   // 8 bf16 (4 VGPRs)
typedef __attribute__((ext_vector_type(4))) float f32x4;
typedef __attribute__((ext_vector_type(2))) float f32x2;

#define T_LEN 2048
#define DMODEL 1024
#define DINNER 2048
#define DSTATE 16
#define LN_EPS 1e-5f
#define NCHUNK 128
#define CLEN 16     // NCHUNK * CLEN == T_LEN
#define SSTR 64     // ssm row stride (36 used, padded to 64)
#define PSEG 131072 // elems per split-K partial (2048*64)

#define GLOBAL_AS __attribute__((address_space(1)))
#define LDS_AS __attribute__((address_space(3)))

__device__ __forceinline__ void g2l16(void* lds, const void* g) {
    __builtin_amdgcn_global_load_lds((const GLOBAL_AS void*)g, (LDS_AS void*)lds, 16, 0, 0);
}

__device__ __forceinline__ float b2f(short s) {
    return __uint_as_float(((unsigned)(unsigned short)s) << 16);
}

__device__ __forceinline__ unsigned short f2bu(float f) {
    bf16 b = __float2bfloat16(f);
    return *reinterpret_cast<unsigned short*>(&b);
}

// buf element j of a row held as f32x4 vectors; j must be compile-time const
#define BG(buf, j) (buf[(j) >> 2][(j) & 3])

// ---------- weight preps + LayerNorm in ONE launch ----------
// W_x column remap so ssm rows are: col 0 = dt_raw, cols 4..19 = B, cols 20..35 = C.
__global__ void prep_all(const float* __restrict__ Win, const float* __restrict__ Wout,
                         const float* __restrict__ Wx, const float* __restrict__ x,
                         const float* __restrict__ lng, const float* __restrict__ lnb,
                         bf16* __restrict__ WinT, bf16* __restrict__ WoutT,
                         bf16* __restrict__ WxT, bf16* __restrict__ xn) {
    __shared__ float t[32][33];
    int bid = blockIdx.x, tid = threadIdx.x;
    int tx = tid & 31, ty4 = (tid >> 5) * 4;
    if (bid < 4096) {               // W_in [1024][4096] -> WinT [4096][1024]
        int n0 = (bid & 127) * 32, k0 = (bid >> 7) * 32;
#pragma unroll
        for (int r = 0; r < 4; r++)
            t[ty4 + r][tx] = Win[(size_t)(k0 + ty4 + r) * 4096 + n0 + tx];
        __syncthreads();
#pragma unroll
        for (int r = 0; r < 4; r++)
            WinT[(size_t)(n0 + ty4 + r) * 1024 + k0 + tx] = __float2bfloat16(t[tx][ty4 + r]);
    } else if (bid < 6144) {        // W_out [2048][1024] -> WoutT [1024][2048]
        int b = bid - 4096;
        int n0 = (b & 31) * 32, k0 = (b >> 5) * 32;
#pragma unroll
        for (int r = 0; r < 4; r++)
            t[ty4 + r][tx] = Wout[(size_t)(k0 + ty4 + r) * 1024 + n0 + tx];
        __syncthreads();
#pragma unroll
        for (int r = 0; r < 4; r++)
            WoutT[(size_t)(n0 + ty4 + r) * 2048 + k0 + tx] = __float2bfloat16(t[tx][ty4 + r]);
    } else if (bid < 6656) {        // W_x [2048][33] -> WxT [64][2048], remapped + zero-pad
        int idx = (bid - 6144) * 256 + tid;
        int n = idx >> 11, k = idx & 2047;
        int j = (n == 0) ? 0 : (n >= 4 && n <= 35) ? n - 3 : -1;
        WxT[idx] = __float2bfloat16(j >= 0 ? Wx[k * 33 + j] : 0.f);
    } else {                        // LayerNorm row
        int row = bid - 6656;
        const float* xr = x + (size_t)row * DMODEL;
        float v[4];
        float s = 0.f, q = 0.f;
#pragma unroll
        for (int i = 0; i < 4; i++) {
            v[i] = xr[tid + i * 256];
            s += v[i];
            q += v[i] * v[i];
        }
        __shared__ float sh_s[256], sh_q[256];
        sh_s[tid] = s; sh_q[tid] = q;
        __syncthreads();
        for (int st = 128; st > 0; st >>= 1) {
            if (tid < st) { sh_s[tid] += sh_s[tid + st]; sh_q[tid] += sh_q[tid + st]; }
            __syncthreads();
        }
        float mean = sh_s[0] * (1.f / DMODEL);
        float var  = sh_q[0] * (1.f / DMODEL) - mean * mean;
        float rstd = rsqrtf(var + LN_EPS);
#pragma unroll
        for (int i = 0; i < 4; i++) {
            int c = tid + i * 256;
            xn[(size_t)row * DMODEL + c] =
                __float2bfloat16((v[i] - mean) * rstd * lng[c] + lnb[c]);
        }
    }
}

// ---------- MFMA GEMM: C = A[M][lda](bf16) * Bt[N][lda](bf16)^T ----------
template <int BM, int BN, int WAVE_M, int WAVE_N, int WRITE_RESID, int OUT_BF16>
__global__ void gemm_mfma(const bf16* __restrict__ A, const bf16* __restrict__ Bt,
                          void* __restrict__ Cv, const float* __restrict__ resid,
                          int M, int N, int Kslice, int lda) {
    constexpr int WMsz = BM / WAVE_M;
    constexpr int WNsz = BN / WAVE_N;
    constexpr int TM = WMsz / 16;
    constexpr int TN = WNsz / 16;
    __shared__ short As[BM * 64];
    __shared__ short Bs[BN * 64];
    int tid = threadIdx.x;
    int lane = tid & 63, wave = tid >> 6;
    int wm = (wave / WAVE_N) * WMsz, wn = (wave % WAVE_N) * WNsz;
    int rowBase = blockIdx.y * BM, colBase = blockIdx.x * BN;
    int kbase = blockIdx.z * Kslice;

    f32x4 acc[TM][TN];
#pragma unroll
    for (int i = 0; i < TM; i++)
#pragma unroll
        for (int j = 0; j < TN; j++) acc[i][j] = f32x4{0.f, 0.f, 0.f, 0.f};

    int srow = tid >> 3;
    int cc = (tid & 7) ^ (srow & 7);
    const int ldsoff = tid * 16;

    for (int k0 = kbase; k0 < kbase + Kslice; k0 += 64) {
#pragma unroll
        for (int j = 0; j < BM / 32; j++)
            g2l16((char*)As + j * 4096 + ldsoff,
                  A + (size_t)(rowBase + j * 32 + srow) * lda + k0 + cc * 8);
#pragma unroll
        for (int j = 0; j < BN / 32; j++)
            g2l16((char*)Bs + j * 4096 + ldsoff,
                  Bt + (size_t)(colBase + j * 32 + srow) * lda + k0 + cc * 8);
        __syncthreads();
#pragma unroll
        for (int ks = 0; ks < 2; ks++) {
            bf16x8 af[TM], bfr[TN];
#pragma unroll
            for (int i = 0; i < TM; i++) {
                int row = wm + i * 16 + (lane & 15);
                int slot = (ks * 4 + (lane >> 4)) ^ (row & 7);
                af[i] = *(const bf16x8*)((const char*)As + row * 128 + slot * 16);
            }
#pragma unroll
            for (int j = 0; j < TN; j++) {
                int row = wn + j * 16 + (lane & 15);
                int slot = (ks * 4 + (lane >> 4)) ^ (row & 7);
                bfr[j] = *(const bf16x8*)((const char*)Bs + row * 128 + slot * 16);
            }
#pragma unroll
            for (int i = 0; i < TM; i++)
#pragma unroll
                for (int j = 0; j < TN; j++)
                    acc[i][j] = __builtin_amdgcn_mfma_f32_16x16x32_bf16(
                        af[i], bfr[j], acc[i][j], 0, 0, 0);
        }
        __syncthreads();
    }
    int rq = lane >> 4, cn = lane & 15;
    float* Cf = (float*)Cv + (size_t)blockIdx.z * M * N;
#pragma unroll
    for (int i = 0; i < TM; i++) {
#pragma unroll
        for (int j = 0; j < TN; j++) {
#pragma unroll
            for (int r = 0; r < 4; r++) {
                size_t row = rowBase + wm + i * 16 + rq * 4 + r;
                int col = colBase + wn + j * 16 + cn;
                float v = acc[i][j][r];
                if (WRITE_RESID) v += resid[row * N + col];
                if (OUT_BF16)
                    ((bf16*)Cv)[row * N + col] = __float2bfloat16(v);
                else
                    Cf[row * N + col] = v;
            }
        }
    }
}

// ---------- Causal depthwise conv(4) + SiLU, 4-wide over d ----------
__global__ void conv_silu(const bf16* __restrict__ xz, const float* __restrict__ cw,
                          const float* __restrict__ cb, bf16* __restrict__ xc) {
    int idx = blockIdx.x * 256 + threadIdx.x;   // T_LEN * DINNER/4 threads
    int t = idx >> 9, d4 = (idx & 511) * 4;
    const f32x4 bv = *(const f32x4*)(cb + d4);
    float acc0 = bv[0], acc1 = bv[1], acc2 = bv[2], acc3 = bv[3];
    const f32x4* cwv = (const f32x4*)(cw + d4 * 4);  // rows d4..d4+3
    f32x4 w0 = cwv[0], w1 = cwv[1], w2 = cwv[2], w3 = cwv[3];
#pragma unroll
    for (int k = 0; k < 4; k++) {
        int tt = t - 3 + k;
        if (tt >= 0) {
            ushort4 v = *(const ushort4*)((const short*)xz + (size_t)tt * (2 * DINNER) + d4);
            acc0 = fmaf(b2f((short)v.x), w0[k], acc0);
            acc1 = fmaf(b2f((short)v.y), w1[k], acc1);
            acc2 = fmaf(b2f((short)v.z), w2[k], acc2);
            acc3 = fmaf(b2f((short)v.w), w3[k], acc3);
        }
    }
    ushort4 o;
    o.x = f2bu(acc0 / (1.f + __expf(-acc0)));
    o.y = f2bu(acc1 / (1.f + __expf(-acc1)));
    o.z = f2bu(acc2 / (1.f + __expf(-acc2)));
    o.w = f2bu(acc3 / (1.f + __expf(-acc3)));
    *(ushort4*)((short*)xc + (size_t)t * DINNER + d4) = o;
}

// ---------- sum the 4 split-K partials once: ssm[t][64] ----------
__global__ void reduce_parts(const float* __restrict__ parts, float* __restrict__ ssm) {
    int idx = (blockIdx.x * 256 + threadIdx.x) * 4;
    f32x4 a = *(const f32x4*)(parts + idx);
    f32x4 b = *(const f32x4*)(parts + idx + PSEG);
    f32x4 c = *(const f32x4*)(parts + idx + 2 * PSEG);
    f32x4 d = *(const f32x4*)(parts + idx + 3 * PSEG);
    *(f32x4*)(ssm + idx) = (a + b) + (c + d);
}

__device__ __forceinline__ float softplus_f(float pre) {
    return (pre > 20.f) ? pre : log1pf(__expf(pre));
}

// q^1..q^16 in a[0..15], log-depth
__device__ __forceinline__ void powtree(float q, float* a) {
    a[0] = q;
    a[1] = q * q;
    a[2] = a[1] * q;
    a[3] = a[1] * a[1];
#pragma unroll
    for (int j = 0; j < 4; j++) a[4 + j] = a[j] * a[3];
#pragma unroll
    for (int j = 0; j < 8; j++) a[8 + j] = a[j] * a[7];
}

__device__ __forceinline__ void ldrow5(f32x4* b, const f32x4* sp) {
#pragma unroll
    for (int k = 0; k < 5; k++) b[k] = sp[k];
}

__device__ __forceinline__ void ldrow8(f32x4* b, const f32x4* sp) {
#pragma unroll
    for (int k = 0; k < 8; k++) b[k] = sp[k];
}

// ---------- Scan pass 1 step + pipelined loop ----------
// buf = 5 vecs: col 0 = dt_raw, cols 4..19 = B. Also emits (dt, q=exp(-dt)).
template <int FAST>
__device__ __forceinline__ void p1_step(const f32x4* buf, short xcs, float wdt, float bd,
                                        const float* A, float& Lsum, float* Sv,
                                        f32x2* dqout) {
    float dt = softplus_f(BG(buf, 0) * wdt + bd);
    float q = __expf(-dt);
    Lsum += dt;
    float u = dt * b2f(xcs);
    *dqout = f32x2{dt, q};
    if (FAST) {
        float a[DSTATE];
        powtree(q, a);
#pragma unroll
        for (int n = 0; n < DSTATE; n++)
            Sv[n] = fmaf(a[n], Sv[n], u * BG(buf, 4 + n));
    } else {
#pragma unroll
        for (int n = 0; n < DSTATE; n++)
            Sv[n] = fmaf(__expf(dt * A[n]), Sv[n], u * BG(buf, 4 + n));
    }
}

// NOTE: prefetch reads one row past the chunk end on the last chunk; ssm has a
// padded tail and the stray xc/dq-adjacent reads stay inside the workspace.
template <int FAST>
__device__ __forceinline__ void p1_loop(const f32x4* sp, const short* xcp,
                                        float wdt, float bd, const float* A,
                                        float& Lsum, float* Sv, f32x2* dqp) {
    f32x4 bA[5], bB[5];
    short xA, xB;
    ldrow5(bA, sp);
    xA = xcp[0];
#pragma unroll
    for (int i = 0; i < CLEN; i += 2) {
        ldrow5(bB, sp + (i + 1) * 16);
        xB = xcp[(size_t)(i + 1) * DINNER];
        p1_step<FAST>(bA, xA, wdt, bd, A, Lsum, Sv, dqp + (size_t)i * DINNER);
        ldrow5(bA, sp + (i + 2) * 16);
        xA = xcp[(size_t)(i + 2) * DINNER];
        p1_step<FAST>(bB, xB, wdt, bd, A, Lsum, Sv, dqp + (size_t)(i + 1) * DINNER);
    }
}

__global__ void scan_pass1(
        const float* __restrict__ ssm, const bf16* __restrict__ xc,
        const float* __restrict__ Wdt, const float* __restrict__ bdt,
        const float* __restrict__ Alog,
        float* __restrict__ Ld, float* __restrict__ S, f32x2* __restrict__ dq) {
    int tid = threadIdx.x;
    int d = blockIdx.x * 256 + tid;
    int c = blockIdx.y;
    int t0 = c * CLEN;
    float A[DSTATE];
    bool fast = true;
#pragma unroll
    for (int n = 0; n < DSTATE; n++) {
        A[n] = -__expf(Alog[d * DSTATE + n]);
        fast = fast && (fabsf(A[n] + (float)(n + 1)) < 1e-3f * (n + 1));
    }
    float wdt = Wdt[d], bd = bdt[d];
    float Sv[DSTATE];
#pragma unroll
    for (int n = 0; n < DSTATE; n++) Sv[n] = 0.f;
    float Lsum = 0.f;
    const f32x4* sp = (const f32x4*)(ssm + (size_t)t0 * SSTR);
    const short* xcp = (const short*)xc + (size_t)t0 * DINNER + d;
    f32x2* dqp = dq + (size_t)t0 * DINNER + d;
    if (fast)
        p1_loop<1>(sp, xcp, wdt, bd, A, Lsum, Sv, dqp);
    else
        p1_loop<0>(sp, xcp, wdt, bd, A, Lsum, Sv, dqp);
    Ld[(size_t)c * DINNER + d] = Lsum;
    size_t base = (size_t)c * DINNER * DSTATE + d;   // [c][n][d]
#pragma unroll
    for (int n = 0; n < DSTATE; n++)
        S[base + (size_t)n * DINNER] = Sv[n];
}

// ---------- Scan pass 2: block-segmented scan over chunks ----------
// grid (DINNER/64, DSTATE), 256 thr = 64 d x 4 segments of 32 chunks.
#define SEGL (NCHUNK / 4)
__global__ void scan_pass2(const float* __restrict__ Ld, const float* __restrict__ S,
                           const float* __restrict__ Alog, float* __restrict__ Hst) {
    int tx = threadIdx.x & 63, ty = threadIdx.x >> 6;
    int d = blockIdx.x * 64 + tx;
    int n = blockIdx.y;
    float A = -__expf(Alog[d * DSTATE + n]);
    int c0 = ty * SEGL;
    float lv[SEGL], sv[SEGL];
#pragma unroll
    for (int j = 0; j < SEGL; j++) {
        int cc = c0 + j;
        lv[j] = Ld[(size_t)cc * DINNER + d];
        sv[j] = S[(size_t)cc * DINNER * DSTATE + (size_t)n * DINNER + d];
    }
    float Lsum = 0.f, Sseg = 0.f;
#pragma unroll
    for (int j = 0; j < SEGL; j++) {
        Sseg = fmaf(__expf(A * lv[j]), Sseg, sv[j]);
        Lsum += lv[j];
    }
    __shared__ float shL[4][64], shS[4][64], shC[4][64];
    shL[ty][tx] = Lsum;
    shS[ty][tx] = Sseg;
    __syncthreads();
    if (ty == 0) {
        float car = 0.f;
        shC[0][tx] = 0.f;
#pragma unroll
        for (int s = 0; s < 3; s++) {
            car = fmaf(__expf(A * shL[s][tx]), car, shS[s][tx]);
            shC[s + 1][tx] = car;
        }
    }
    __syncthreads();
    float H = shC[ty][tx];
#pragma unroll
    for (int j = 0; j < SEGL; j++) {
        size_t o = (size_t)(c0 + j) * DINNER * DSTATE + (size_t)n * DINNER + d;
        Hst[o] = H;
        H = fmaf(__expf(A * lv[j]), H, sv[j]);
    }
}

// ---------- Scan pass 3 step + pipelined loop, fused epilogue ----------
// buf = 8 vecs: cols 4..35 of the ssm row => B at idx 0..15, C at idx 16..31.
// dt/q arrive precomputed from pass1 via dq (kills the softplus/exp chain).
template <int FAST>
__device__ __forceinline__ void p3_step(const f32x4* buf, f32x2 dq, short xcs, short zs,
                                        float Dd, const float* A,
                                        float* h, bf16* outp) {
    float dt = dq[0], q = dq[1];
    float xcf = b2f(xcs);
    float u = dt * xcf;
    float y;
    if (FAST) {
        float a[DSTATE];
        powtree(q, a);
        float y0 = 0.f, y1 = 0.f, y2 = 0.f, y3 = 0.f;
#pragma unroll
        for (int n = 0; n < 4; n++) {
            h[n]      = fmaf(a[n],      h[n],      u * BG(buf, n));
            y0 = fmaf(h[n],      BG(buf, 16 + n), y0);
            h[n + 4]  = fmaf(a[n + 4],  h[n + 4],  u * BG(buf, 4 + n));
            y1 = fmaf(h[n + 4],  BG(buf, 20 + n), y1);
            h[n + 8]  = fmaf(a[n + 8],  h[n + 8],  u * BG(buf, 8 + n));
            y2 = fmaf(h[n + 8],  BG(buf, 24 + n), y2);
            h[n + 12] = fmaf(a[n + 12], h[n + 12], u * BG(buf, 12 + n));
            y3 = fmaf(h[n + 12], BG(buf, 28 + n), y3);
        }
        y = (y0 + y1) + (y2 + y3);
    } else {
        y = 0.f;
#pragma unroll
        for (int n = 0; n < DSTATE; n++) {
            float a = __expf(dt * A[n]);
            h[n] = fmaf(a, h[n], u * BG(buf, n));
            y = fmaf(h[n], BG(buf, 16 + n), y);
        }
    }
    float z = b2f(zs);
    float sz = z / (1.f + __expf(-z));
    *outp = __float2bfloat16(fmaf(xcf, Dd, y) * sz);
}

template <int FAST>
__device__ __forceinline__ void p3_loop(const f32x4* sp8, const f32x2* dqp,
                                        const short* xcp, const short* zp,
                                        float Dd, const float* A,
                                        float* h, bf16* yp) {
    f32x4 bA[8], bB[8];
    f32x2 qA, qB;
    short xA, xB, zA, zB;
    ldrow8(bA, sp8);
    qA = dqp[0];
    xA = xcp[0];
    zA = zp[0];
#pragma unroll
    for (int i = 0; i < CLEN; i += 2) {
        ldrow8(bB, sp8 + (i + 1) * 16);
        qB = dqp[(size_t)(i + 1) * DINNER];
        xB = xcp[(size_t)(i + 1) * DINNER];
        zB = zp[(size_t)(i + 1) * 2 * DINNER];
        p3_step<FAST>(bA, qA, xA, zA, Dd, A, h, yp + (size_t)i * DINNER);
        ldrow8(bA, sp8 + (i + 2) * 16);
        qA = dqp[(size_t)(i + 2) * DINNER];
        xA = xcp[(size_t)(i + 2) * DINNER];
        zA = zp[(size_t)(i + 2) * 2 * DINNER];
        p3_step<FAST>(bB, qB, xB, zB, Dd, A, h, yp + (size_t)(i + 1) * DINNER);
    }
}

__global__ void scan_pass3(
        const float* __restrict__ ssm, const f32x2* __restrict__ dq,
        const bf16* __restrict__ xc, const bf16* __restrict__ xz,
        const float* __restrict__ Alog, const float* __restrict__ Dp,
        const float* __restrict__ Hst, bf16* __restrict__ yf) {
    int tid = threadIdx.x;
    int d = blockIdx.x * 256 + tid;
    int c = blockIdx.y;
    int t0 = c * CLEN;
    float A[DSTATE], h[DSTATE];
    bool fast = true;
    size_t base = (size_t)c * DINNER * DSTATE + d;
#pragma unroll
    for (int n = 0; n < DSTATE; n++) {
        A[n] = -__expf(Alog[d * DSTATE + n]);
        fast = fast && (fabsf(A[n] + (float)(n + 1)) < 1e-3f * (n + 1));
        h[n] = Hst[base + (size_t)n * DINNER];
    }
    float Dd = Dp[d];
    const f32x4* sp8 = (const f32x4*)(ssm + (size_t)t0 * SSTR) + 1;
    const f32x2* dqp = dq + (size_t)t0 * DINNER + d;
    const short* xcp = (const short*)xc + (size_t)t0 * DINNER + d;
    const short* zp  = (const short*)xz + (size_t)t0 * (2 * DINNER) + DINNER + d;
    bf16* yp = yf + (size_t)t0 * DINNER + d;
    if (fast)
        p3_loop<1>(sp8, dqp, xcp, zp, Dd, A, h, yp);
    else
        p3_loop<0>(sp8, dqp, xcp, zp, Dd, A, h, yp);
}

extern "C" void kernel_launch(void* const* d_in, const int* in_sizes, int n_in,
                              void* d_out, int out_size, void* d_ws, size_t ws_size,
                              hipStream_t stream) {
    const float* x     = (const float*)d_in[0];
    const float* W_in  = (const float*)d_in[1];
    const float* convw = (const float*)d_in[2];
    const float* convb = (const float*)d_in[3];
    const float* W_x   = (const float*)d_in[4];
    const float* W_dt  = (const float*)d_in[5];
    const float* b_dt  = (const float*)d_in[6];
    const float* A_log = (const float*)d_in[7];
    const float* Dp    = (const float*)d_in[8];
    const float* W_out = (const float*)d_in[9];
    const float* ln_g  = (const float*)d_in[10];
    const float* ln_b  = (const float*)d_in[11];
    float* out = (float*)d_out;

    // ~118 MB of the 256 MiB workspace; no aliasing. ssm has a padded tail row
    // (prefetch reads one row past the end); dq tail prefetch stays in-workspace.
    char* wsb = (char*)d_ws;
    bf16*  xn    = (bf16*)(wsb);                    //  4 MB
    bf16*  WinT  = (bf16*)(wsb + (4ull  << 20));    //  8 MB
    bf16*  WoutT = (bf16*)(wsb + (12ull << 20));    //  4 MB
    bf16*  WxT   = (bf16*)(wsb + (16ull << 20));    //  0.25 MB
    bf16*  xz    = (bf16*)(wsb + (17ull << 20));    // 16 MB
    bf16*  xc    = (bf16*)(wsb + (33ull << 20));    //  8 MB
    float* parts = (float*)(wsb + (41ull << 20));   //  2 MB (4 x 2048x64)
    float* Ld    = (float*)(wsb + (43ull << 20));   //  1 MB (128 x 2048)
    float* Hst   = (float*)(wsb + (44ull << 20));   // 16 MB
    float* S     = (float*)(wsb + (60ull << 20));   // 16 MB
    bf16*  yf    = (bf16*)(wsb + (76ull << 20));    //  8 MB
    float* ssm   = (float*)(wsb + (84ull << 20));   //  0.5 MB + pad
    f32x2* dq    = (f32x2*)(wsb + (86ull << 20));   // 32 MB (2048 x 2048 x float2)

    prep_all<<<8704, 256, 0, stream>>>(W_in, W_out, W_x, x, ln_g, ln_b,
                                       WinT, WoutT, WxT, xn);

    gemm_mfma<128, 128, 2, 2, 0, 1><<<dim3(4096 / 128, 2048 / 128), 256, 0, stream>>>(
        xn, WinT, xz, nullptr, 2048, 4096, 1024, 1024);

    conv_silu<<<(T_LEN * DINNER / 4) / 256, 256, 0, stream>>>(xz, convw, convb, xc);

    gemm_mfma<32, 64, 2, 2, 0, 0><<<dim3(1, 2048 / 32, 4), 256, 0, stream>>>(
        xc, WxT, parts, nullptr, 2048, 64, 512, 2048);

    reduce_parts<<<(T_LEN * SSTR / 4) / 256, 256, 0, stream>>>(parts, ssm);

    scan_pass1<<<dim3(DINNER / 256, NCHUNK), 256, 0, stream>>>(
        ssm, xc, W_dt, b_dt, A_log, Ld, S, dq);
    scan_pass2<<<dim3(DINNER / 64, DSTATE), 256, 0, stream>>>(Ld, S, A_log, Hst);
    scan_pass3<<<dim3(DINNER / 256, NCHUNK), 256, 0, stream>>>(
        ssm, dq, xc, xz, A_log, Dp, Hst, yf);

    gemm_mfma<64, 64, 2, 2, 1, 0><<<dim3(1024 / 64, 2048 / 64), 256, 0, stream>>>(
        yf, WoutT, out, x, 2048, 1024, 2048, 2048);
}

// Round 12
// 219.622 us; speedup vs baseline: 1.0171x; 1.0084x over previous
//
#include <hip/hip_runtime.h>
#include <hip/hip_bf16.h>

typedef __hip_bfloat16 bf16;
typedef __attribute__((ext_vector_type(8))) short bf16x8;   // 8 bf16 (4 VGPRs)
typedef __attribute__((ext_vector_type(4))) float f32x4;
typedef __attribute__((ext_vector_type(2))) float f32x2;

#define T_LEN 2048
#define DMODEL 1024
#define DINNER 2048
#define DSTATE 16
#define LN_EPS 1e-5f
#define NCHUNK 128
#define CLEN 16     // NCHUNK * CLEN == T_LEN
#define SSTR 64     // ssm row stride (36 used, padded to 64)
#define PSEG 131072 // elems per split-K partial (2048*64)

#define GLOBAL_AS __attribute__((address_space(1)))
#define LDS_AS __attribute__((address_space(3)))

__device__ __forceinline__ void g2l16(void* lds, const void* g) {
    __builtin_amdgcn_global_load_lds((const GLOBAL_AS void*)g, (LDS_AS void*)lds, 16, 0, 0);
}

__device__ __forceinline__ float b2f(short s) {
    return __uint_as_float(((unsigned)(unsigned short)s) << 16);
}

__device__ __forceinline__ unsigned short f2bu(float f) {
    bf16 b = __float2bfloat16(f);
    return *reinterpret_cast<unsigned short*>(&b);
}

// buf element j of a row held as f32x4 vectors; j must be compile-time const
#define BG(buf, j) (buf[(j) >> 2][(j) & 3])

// ---------- weight preps + LayerNorm in ONE launch ----------
// W_x column remap so ssm rows are: col 0 = dt_raw, cols 4..19 = B, cols 20..35 = C.
__global__ void prep_all(const float* __restrict__ Win, const float* __restrict__ Wout,
                         const float* __restrict__ Wx, const float* __restrict__ x,
                         const float* __restrict__ lng, const float* __restrict__ lnb,
                         bf16* __restrict__ WinT, bf16* __restrict__ WoutT,
                         bf16* __restrict__ WxT, bf16* __restrict__ xn) {
    __shared__ float t[32][33];
    int bid = blockIdx.x, tid = threadIdx.x;
    int tx = tid & 31, ty4 = (tid >> 5) * 4;
    if (bid < 4096) {               // W_in [1024][4096] -> WinT [4096][1024]
        int n0 = (bid & 127) * 32, k0 = (bid >> 7) * 32;
#pragma unroll
        for (int r = 0; r < 4; r++)
            t[ty4 + r][tx] = Win[(size_t)(k0 + ty4 + r) * 4096 + n0 + tx];
        __syncthreads();
#pragma unroll
        for (int r = 0; r < 4; r++)
            WinT[(size_t)(n0 + ty4 + r) * 1024 + k0 + tx] = __float2bfloat16(t[tx][ty4 + r]);
    } else if (bid < 6144) {        // W_out [2048][1024] -> WoutT [1024][2048]
        int b = bid - 4096;
        int n0 = (b & 31) * 32, k0 = (b >> 5) * 32;
#pragma unroll
        for (int r = 0; r < 4; r++)
            t[ty4 + r][tx] = Wout[(size_t)(k0 + ty4 + r) * 1024 + n0 + tx];
        __syncthreads();
#pragma unroll
        for (int r = 0; r < 4; r++)
            WoutT[(size_t)(n0 + ty4 + r) * 2048 + k0 + tx] = __float2bfloat16(t[tx][ty4 + r]);
    } else if (bid < 6656) {        // W_x [2048][33] -> WxT [64][2048], remapped + zero-pad
        int idx = (bid - 6144) * 256 + tid;
        int n = idx >> 11, k = idx & 2047;
        int j = (n == 0) ? 0 : (n >= 4 && n <= 35) ? n - 3 : -1;
        WxT[idx] = __float2bfloat16(j >= 0 ? Wx[k * 33 + j] : 0.f);
    } else {                        // LayerNorm row
        int row = bid - 6656;
        const float* xr = x + (size_t)row * DMODEL;
        float v[4];
        float s = 0.f, q = 0.f;
#pragma unroll
        for (int i = 0; i < 4; i++) {
            v[i] = xr[tid + i * 256];
            s += v[i];
            q += v[i] * v[i];
        }
        __shared__ float sh_s[256], sh_q[256];
        sh_s[tid] = s; sh_q[tid] = q;
        __syncthreads();
        for (int st = 128; st > 0; st >>= 1) {
            if (tid < st) { sh_s[tid] += sh_s[tid + st]; sh_q[tid] += sh_q[tid + st]; }
            __syncthreads();
        }
        float mean = sh_s[0] * (1.f / DMODEL);
        float var  = sh_q[0] * (1.f / DMODEL) - mean * mean;
        float rstd = rsqrtf(var + LN_EPS);
#pragma unroll
        for (int i = 0; i < 4; i++) {
            int c = tid + i * 256;
            xn[(size_t)row * DMODEL + c] =
                __float2bfloat16((v[i] - mean) * rstd * lng[c] + lnb[c]);
        }
    }
}

// ---------- MFMA GEMM: C = A[M][lda](bf16) * Bt[N][lda](bf16)^T ----------
template <int BM, int BN, int WAVE_M, int WAVE_N, int WRITE_RESID, int OUT_BF16>
__global__ void gemm_mfma(const bf16* __restrict__ A, const bf16* __restrict__ Bt,
                          void* __restrict__ Cv, const float* __restrict__ resid,
                          int M, int N, int Kslice, int lda) {
    constexpr int WMsz = BM / WAVE_M;
    constexpr int WNsz = BN / WAVE_N;
    constexpr int TM = WMsz / 16;
    constexpr int TN = WNsz / 16;
    __shared__ short As[BM * 64];
    __shared__ short Bs[BN * 64];
    int tid = threadIdx.x;
    int lane = tid & 63, wave = tid >> 6;
    int wm = (wave / WAVE_N) * WMsz, wn = (wave % WAVE_N) * WNsz;
    int rowBase = blockIdx.y * BM, colBase = blockIdx.x * BN;
    int kbase = blockIdx.z * Kslice;

    f32x4 acc[TM][TN];
#pragma unroll
    for (int i = 0; i < TM; i++)
#pragma unroll
        for (int j = 0; j < TN; j++) acc[i][j] = f32x4{0.f, 0.f, 0.f, 0.f};

    int srow = tid >> 3;
    int cc = (tid & 7) ^ (srow & 7);
    const int ldsoff = tid * 16;

    for (int k0 = kbase; k0 < kbase + Kslice; k0 += 64) {
#pragma unroll
        for (int j = 0; j < BM / 32; j++)
            g2l16((char*)As + j * 4096 + ldsoff,
                  A + (size_t)(rowBase + j * 32 + srow) * lda + k0 + cc * 8);
#pragma unroll
        for (int j = 0; j < BN / 32; j++)
            g2l16((char*)Bs + j * 4096 + ldsoff,
                  Bt + (size_t)(colBase + j * 32 + srow) * lda + k0 + cc * 8);
        __syncthreads();
#pragma unroll
        for (int ks = 0; ks < 2; ks++) {
            bf16x8 af[TM], bfr[TN];
#pragma unroll
            for (int i = 0; i < TM; i++) {
                int row = wm + i * 16 + (lane & 15);
                int slot = (ks * 4 + (lane >> 4)) ^ (row & 7);
                af[i] = *(const bf16x8*)((const char*)As + row * 128 + slot * 16);
            }
#pragma unroll
            for (int j = 0; j < TN; j++) {
                int row = wn + j * 16 + (lane & 15);
                int slot = (ks * 4 + (lane >> 4)) ^ (row & 7);
                bfr[j] = *(const bf16x8*)((const char*)Bs + row * 128 + slot * 16);
            }
#pragma unroll
            for (int i = 0; i < TM; i++)
#pragma unroll
                for (int j = 0; j < TN; j++)
                    acc[i][j] = __builtin_amdgcn_mfma_f32_16x16x32_bf16(
                        af[i], bfr[j], acc[i][j], 0, 0, 0);
        }
        __syncthreads();
    }
    int rq = lane >> 4, cn = lane & 15;
    float* Cf = (float*)Cv + (size_t)blockIdx.z * M * N;
#pragma unroll
    for (int i = 0; i < TM; i++) {
#pragma unroll
        for (int j = 0; j < TN; j++) {
#pragma unroll
            for (int r = 0; r < 4; r++) {
                size_t row = rowBase + wm + i * 16 + rq * 4 + r;
                int col = colBase + wn + j * 16 + cn;
                float v = acc[i][j][r];
                if (WRITE_RESID) v += resid[row * N + col];
                if (OUT_BF16)
                    ((bf16*)Cv)[row * N + col] = __float2bfloat16(v);
                else
                    Cf[row * N + col] = v;
            }
        }
    }
}

// ---------- Causal depthwise conv(4) + SiLU, 4-wide over d ----------
__global__ void conv_silu(const bf16* __restrict__ xz, const float* __restrict__ cw,
                          const float* __restrict__ cb, bf16* __restrict__ xc) {
    int idx = blockIdx.x * 256 + threadIdx.x;   // T_LEN * DINNER/4 threads
    int t = idx >> 9, d4 = (idx & 511) * 4;
    const f32x4 bv = *(const f32x4*)(cb + d4);
    float acc0 = bv[0], acc1 = bv[1], acc2 = bv[2], acc3 = bv[3];
    const f32x4* cwv = (const f32x4*)(cw + d4 * 4);  // rows d4..d4+3
    f32x4 w0 = cwv[0], w1 = cwv[1], w2 = cwv[2], w3 = cwv[3];
#pragma unroll
    for (int k = 0; k < 4; k++) {
        int tt = t - 3 + k;
        if (tt >= 0) {
            ushort4 v = *(const ushort4*)((const short*)xz + (size_t)tt * (2 * DINNER) + d4);
            acc0 = fmaf(b2f((short)v.x), w0[k], acc0);
            acc1 = fmaf(b2f((short)v.y), w1[k], acc1);
            acc2 = fmaf(b2f((short)v.z), w2[k], acc2);
            acc3 = fmaf(b2f((short)v.w), w3[k], acc3);
        }
    }
    ushort4 o;
    o.x = f2bu(acc0 / (1.f + __expf(-acc0)));
    o.y = f2bu(acc1 / (1.f + __expf(-acc1)));
    o.z = f2bu(acc2 / (1.f + __expf(-acc2)));
    o.w = f2bu(acc3 / (1.f + __expf(-acc3)));
    *(ushort4*)((short*)xc + (size_t)t * DINNER + d4) = o;
}

// ---------- sum the 4 split-K partials once: ssm[t][64] ----------
__global__ void reduce_parts(const float* __restrict__ parts, float* __restrict__ ssm) {
    int idx = (blockIdx.x * 256 + threadIdx.x) * 4;
    f32x4 a = *(const f32x4*)(parts + idx);
    f32x4 b = *(const f32x4*)(parts + idx + PSEG);
    f32x4 c = *(const f32x4*)(parts + idx + 2 * PSEG);
    f32x4 d = *(const f32x4*)(parts + idx + 3 * PSEG);
    *(f32x4*)(ssm + idx) = (a + b) + (c + d);
}

__device__ __forceinline__ float softplus_f(float pre) {
    return (pre > 20.f) ? pre : log1pf(__expf(pre));
}

// q^1..q^16 in a[0..15], log-depth
__device__ __forceinline__ void powtree(float q, float* a) {
    a[0] = q;
    a[1] = q * q;
    a[2] = a[1] * q;
    a[3] = a[1] * a[1];
#pragma unroll
    for (int j = 0; j < 4; j++) a[4 + j] = a[j] * a[3];
#pragma unroll
    for (int j = 0; j < 8; j++) a[8 + j] = a[j] * a[7];
}

__device__ __forceinline__ void ldrow4(f32x4* b, const f32x4* sp) {
#pragma unroll
    for (int k = 0; k < 4; k++) b[k] = sp[k];
}

__device__ __forceinline__ void ldrow8(f32x4* b, const f32x4* sp) {
#pragma unroll
    for (int k = 0; k < 8; k++) b[k] = sp[k];
}

// ---------- Scan pass 1: TWO-PHASE ----------
// Phase A: bulk dt/q (16 independent softplus/exp chains -> full ILP; the
// transcendentals leave the serial scan chain entirely), Lsum prefix, dq store.
// Phase B: scan loop = powtree + FMAs only; powtree(i+1) is independent of
// step i's FMAs, so only the 16-deep Sv FMA chain stays serial.
__global__ void scan_pass1(
        const float* __restrict__ ssm, const bf16* __restrict__ xc,
        const float* __restrict__ Wdt, const float* __restrict__ bdt,
        const float* __restrict__ Alog,
        float* __restrict__ Ld, float* __restrict__ S, f32x2* __restrict__ dq) {
    int tid = threadIdx.x;
    int d = blockIdx.x * 256 + tid;
    int c = blockIdx.y;
    int t0 = c * CLEN;
    float A[DSTATE];
    bool fast = true;
#pragma unroll
    for (int n = 0; n < DSTATE; n++) {
        A[n] = -__expf(Alog[d * DSTATE + n]);
        fast = fast && (fabsf(A[n] + (float)(n + 1)) < 1e-3f * (n + 1));
    }
    float wdt = Wdt[d], bd = bdt[d];
    const float* srow = ssm + (size_t)t0 * SSTR;
    const short* xcp = (const short*)xc + (size_t)t0 * DINNER + d;

    // ---- phase A ----
    float dtv[CLEN], qv[CLEN];
#pragma unroll
    for (int i = 0; i < CLEN; i++)
        dtv[i] = softplus_f(srow[i * SSTR] * wdt + bd);   // uniform s_load, indep.
#pragma unroll
    for (int i = 0; i < CLEN; i++)
        qv[i] = __expf(-dtv[i]);                          // indep.
    short xcv[CLEN];
#pragma unroll
    for (int i = 0; i < CLEN; i++)
        xcv[i] = xcp[(size_t)i * DINNER];
    float Lsum = 0.f;
    f32x2* dqp = dq + (size_t)t0 * DINNER + d;
#pragma unroll
    for (int i = 0; i < CLEN; i++) {
        Lsum += dtv[i];
        dqp[(size_t)i * DINNER] = f32x2{dtv[i], qv[i]};
    }
    Ld[(size_t)c * DINNER + d] = Lsum;

    // ---- phase B ----
    float Sv[DSTATE];
#pragma unroll
    for (int n = 0; n < DSTATE; n++) Sv[n] = 0.f;
    if (fast) {
#pragma unroll
        for (int i = 0; i < CLEN; i++) {
            f32x4 bB[4];
            ldrow4(bB, (const f32x4*)(srow + i * SSTR + 4));   // cols 4..19 (B)
            float u = dtv[i] * b2f(xcv[i]);
            float a[DSTATE];
            powtree(qv[i], a);
#pragma unroll
            for (int n = 0; n < DSTATE; n++)
                Sv[n] = fmaf(a[n], Sv[n], u * bB[n >> 2][n & 3]);
        }
    } else {
#pragma unroll
        for (int i = 0; i < CLEN; i++) {
            f32x4 bB[4];
            ldrow4(bB, (const f32x4*)(srow + i * SSTR + 4));
            float u = dtv[i] * b2f(xcv[i]);
#pragma unroll
            for (int n = 0; n < DSTATE; n++)
                Sv[n] = fmaf(__expf(dtv[i] * A[n]), Sv[n], u * bB[n >> 2][n & 3]);
        }
    }
    size_t base = (size_t)c * DINNER * DSTATE + d;   // [c][n][d]
#pragma unroll
    for (int n = 0; n < DSTATE; n++)
        S[base + (size_t)n * DINNER] = Sv[n];
}

// ---------- Scan pass 2: block-segmented scan over chunks ----------
// grid (DINNER/64, DSTATE), 256 thr = 64 d x 4 segments of 32 chunks.
#define SEGL (NCHUNK / 4)
__global__ void scan_pass2(const float* __restrict__ Ld, const float* __restrict__ S,
                           const float* __restrict__ Alog, float* __restrict__ Hst) {
    int tx = threadIdx.x & 63, ty = threadIdx.x >> 6;
    int d = blockIdx.x * 64 + tx;
    int n = blockIdx.y;
    float A = -__expf(Alog[d * DSTATE + n]);
    int c0 = ty * SEGL;
    float lv[SEGL], sv[SEGL];
#pragma unroll
    for (int j = 0; j < SEGL; j++) {
        int cc = c0 + j;
        lv[j] = Ld[(size_t)cc * DINNER + d];
        sv[j] = S[(size_t)cc * DINNER * DSTATE + (size_t)n * DINNER + d];
    }
    float Lsum = 0.f, Sseg = 0.f;
#pragma unroll
    for (int j = 0; j < SEGL; j++) {
        Sseg = fmaf(__expf(A * lv[j]), Sseg, sv[j]);
        Lsum += lv[j];
    }
    __shared__ float shL[4][64], shS[4][64], shC[4][64];
    shL[ty][tx] = Lsum;
    shS[ty][tx] = Sseg;
    __syncthreads();
    if (ty == 0) {
        float car = 0.f;
        shC[0][tx] = 0.f;
#pragma unroll
        for (int s = 0; s < 3; s++) {
            car = fmaf(__expf(A * shL[s][tx]), car, shS[s][tx]);
            shC[s + 1][tx] = car;
        }
    }
    __syncthreads();
    float H = shC[ty][tx];
#pragma unroll
    for (int j = 0; j < SEGL; j++) {
        size_t o = (size_t)(c0 + j) * DINNER * DSTATE + (size_t)n * DINNER + d;
        Hst[o] = H;
        H = fmaf(__expf(A * lv[j]), H, sv[j]);
    }
}

// ---------- Scan pass 3 step + pipelined loop, fused epilogue ----------
// buf = 8 vecs: cols 4..35 of the ssm row => B at idx 0..15, C at idx 16..31.
// dt/q arrive precomputed from pass1 via dq (kills the softplus/exp chain).
template <int FAST>
__device__ __forceinline__ void p3_step(const f32x4* buf, f32x2 dq, short xcs, short zs,
                                        float Dd, const float* A,
                                        float* h, bf16* outp) {
    float dt = dq[0], q = dq[1];
    float xcf = b2f(xcs);
    float u = dt * xcf;
    float y;
    if (FAST) {
        float a[DSTATE];
        powtree(q, a);
        float y0 = 0.f, y1 = 0.f, y2 = 0.f, y3 = 0.f;
#pragma unroll
        for (int n = 0; n < 4; n++) {
            h[n]      = fmaf(a[n],      h[n],      u * BG(buf, n));
            y0 = fmaf(h[n],      BG(buf, 16 + n), y0);
            h[n + 4]  = fmaf(a[n + 4],  h[n + 4],  u * BG(buf, 4 + n));
            y1 = fmaf(h[n + 4],  BG(buf, 20 + n), y1);
            h[n + 8]  = fmaf(a[n + 8],  h[n + 8],  u * BG(buf, 8 + n));
            y2 = fmaf(h[n + 8],  BG(buf, 24 + n), y2);
            h[n + 12] = fmaf(a[n + 12], h[n + 12], u * BG(buf, 12 + n));
            y3 = fmaf(h[n + 12], BG(buf, 28 + n), y3);
        }
        y = (y0 + y1) + (y2 + y3);
    } else {
        y = 0.f;
#pragma unroll
        for (int n = 0; n < DSTATE; n++) {
            float a = __expf(dt * A[n]);
            h[n] = fmaf(a, h[n], u * BG(buf, n));
            y = fmaf(h[n], BG(buf, 16 + n), y);
        }
    }
    float z = b2f(zs);
    float sz = z / (1.f + __expf(-z));
    *outp = __float2bfloat16(fmaf(xcf, Dd, y) * sz);
}

template <int FAST>
__device__ __forceinline__ void p3_loop(const f32x4* sp8, const f32x2* dqp,
                                        const short* xcp, const short* zp,
                                        float Dd, const float* A,
                                        float* h, bf16* yp) {
    f32x4 bA[8], bB[8];
    f32x2 qA, qB;
    short xA, xB, zA, zB;
    ldrow8(bA, sp8);
    qA = dqp[0];
    xA = xcp[0];
    zA = zp[0];
#pragma unroll
    for (int i = 0; i < CLEN; i += 2) {
        ldrow8(bB, sp8 + (i + 1) * 16);
        qB = dqp[(size_t)(i + 1) * DINNER];
        xB = xcp[(size_t)(i + 1) * DINNER];
        zB = zp[(size_t)(i + 1) * 2 * DINNER];
        p3_step<FAST>(bA, qA, xA, zA, Dd, A, h, yp + (size_t)i * DINNER);
        ldrow8(bA, sp8 + (i + 2) * 16);
        qA = dqp[(size_t)(i + 2) * DINNER];
        xA = xcp[(size_t)(i + 2) * DINNER];
        zA = zp[(size_t)(i + 2) * 2 * DINNER];
        p3_step<FAST>(bB, qB, xB, zB, Dd, A, h, yp + (size_t)(i + 1) * DINNER);
    }
}

__global__ void scan_pass3(
        const float* __restrict__ ssm, const f32x2* __restrict__ dq,
        const bf16* __restrict__ xc, const bf16* __restrict__ xz,
        const float* __restrict__ Alog, const float* __restrict__ Dp,
        const float* __restrict__ Hst, bf16* __restrict__ yf) {
    int tid = threadIdx.x;
    int d = blockIdx.x * 256 + tid;
    int c = blockIdx.y;
    int t0 = c * CLEN;
    float A[DSTATE], h[DSTATE];
    bool fast = true;
    size_t base = (size_t)c * DINNER * DSTATE + d;
#pragma unroll
    for (int n = 0; n < DSTATE; n++) {
        A[n] = -__expf(Alog[d * DSTATE + n]);
        fast = fast && (fabsf(A[n] + (float)(n + 1)) < 1e-3f * (n + 1));
        h[n] = Hst[base + (size_t)n * DINNER];
    }
    float Dd = Dp[d];
    const f32x4* sp8 = (const f32x4*)(ssm + (size_t)t0 * SSTR) + 1;
    const f32x2* dqp = dq + (size_t)t0 * DINNER + d;
    const short* xcp = (const short*)xc + (size_t)t0 * DINNER + d;
    const short* zp  = (const short*)xz + (size_t)t0 * (2 * DINNER) + DINNER + d;
    bf16* yp = yf + (size_t)t0 * DINNER + d;
    if (fast)
        p3_loop<1>(sp8, dqp, xcp, zp, Dd, A, h, yp);
    else
        p3_loop<0>(sp8, dqp, xcp, zp, Dd, A, h, yp);
}

extern "C" void kernel_launch(void* const* d_in, const int* in_sizes, int n_in,
                              void* d_out, int out_size, void* d_ws, size_t ws_size,
                              hipStream_t stream) {
    const float* x     = (const float*)d_in[0];
    const float* W_in  = (const float*)d_in[1];
    const float* convw = (const float*)d_in[2];
    const float* convb = (const float*)d_in[3];
    const float* W_x   = (const float*)d_in[4];
    const float* W_dt  = (const float*)d_in[5];
    const float* b_dt  = (const float*)d_in[6];
    const float* A_log = (const float*)d_in[7];
    const float* Dp    = (const float*)d_in[8];
    const float* W_out = (const float*)d_in[9];
    const float* ln_g  = (const float*)d_in[10];
    const float* ln_b  = (const float*)d_in[11];
    float* out = (float*)d_out;

    // ~118 MB of the 256 MiB workspace; no aliasing. ssm has a padded tail row;
    // dq tail prefetch stays in-workspace.
    char* wsb = (char*)d_ws;
    bf16*  xn    = (bf16*)(wsb);                    //  4 MB
    bf16*  WinT  = (bf16*)(wsb + (4ull  << 20));    //  8 MB
    bf16*  WoutT = (bf16*)(wsb + (12ull << 20));    //  4 MB
    bf16*  WxT   = (bf16*)(wsb + (16ull << 20));    //  0.25 MB
    bf16*  xz    = (bf16*)(wsb + (17ull << 20));    // 16 MB
    bf16*  xc    = (bf16*)(wsb + (33ull << 20));    //  8 MB
    float* parts = (float*)(wsb + (41ull << 20));   //  2 MB (4 x 2048x64)
    float* Ld    = (float*)(wsb + (43ull << 20));   //  1 MB (128 x 2048)
    float* Hst   = (float*)(wsb + (44ull << 20));   // 16 MB
    float* S     = (float*)(wsb + (60ull << 20));   // 16 MB
    bf16*  yf    = (bf16*)(wsb + (76ull << 20));    //  8 MB
    float* ssm   = (float*)(wsb + (84ull << 20));   //  0.5 MB + pad
    f32x2* dq    = (f32x2*)(wsb + (86ull << 20));   // 32 MB (2048 x 2048 x float2)

    prep_all<<<8704, 256, 0, stream>>>(W_in, W_out, W_x, x, ln_g, ln_b,
                                       WinT, WoutT, WxT, xn);

    gemm_mfma<128, 128, 2, 2, 0, 1><<<dim3(4096 / 128, 2048 / 128), 256, 0, stream>>>(
        xn, WinT, xz, nullptr, 2048, 4096, 1024, 1024);

    conv_silu<<<(T_LEN * DINNER / 4) / 256, 256, 0, stream>>>(xz, convw, convb, xc);

    gemm_mfma<32, 64, 2, 2, 0, 0><<<dim3(1, 2048 / 32, 4), 256, 0, stream>>>(
        xc, WxT, parts, nullptr, 2048, 64, 512, 2048);

    reduce_parts<<<(T_LEN * SSTR / 4) / 256, 256, 0, stream>>>(parts, ssm);

    scan_pass1<<<dim3(DINNER / 256, NCHUNK), 256, 0, stream>>>(
        ssm, xc, W_dt, b_dt, A_log, Ld, S, dq);
    scan_pass2<<<dim3(DINNER / 64, DSTATE), 256, 0, stream>>>(Ld, S, A_log, Hst);
    scan_pass3<<<dim3(DINNER / 256, NCHUNK), 256, 0, stream>>>(
        ssm, dq, xc, xz, A_log, Dp, Hst, yf);

    gemm_mfma<64, 64, 2, 2, 1, 0><<<dim3(1024 / 64, 2048 / 64), 256, 0, stream>>>(
        yf, WoutT, out, x, 2048, 1024, 2048, 2048);
}

// Round 13
// 219.056 us; speedup vs baseline: 1.0197x; 1.0026x over previous
//
#include <hip/hip_runtime.h>
#include <hip/hip_bf16.h>

typedef __hip_bfloat16 bf16;
typedef __attribute__((ext_vector_type(8))) short bf16x8;   // 8 bf16 (4 VGPRs)
typedef __attribute__((ext_vector_type(4))) float f32x4;
typedef __attribute__((ext_vector_type(2))) float f32x2;

#define T_LEN 2048
#define DMODEL 1024
#define DINNER 2048
#define DSTATE 16
#define LN_EPS 1e-5f
#define NCHUNK 128
#define CLEN 16     // NCHUNK * CLEN == T_LEN
#define SSTR 64     // ssm row stride (36 used, padded to 64)

#define GLOBAL_AS __attribute__((address_space(1)))
#define LDS_AS __attribute__((address_space(3)))

__device__ __forceinline__ void g2l16(void* lds, const void* g) {
    __builtin_amdgcn_global_load_lds((const GLOBAL_AS void*)g, (LDS_AS void*)lds, 16, 0, 0);
}

__device__ __forceinline__ float b2f(short s) {
    return __uint_as_float(((unsigned)(unsigned short)s) << 16);
}

__device__ __forceinline__ unsigned short f2bu(float f) {
    bf16 b = __float2bfloat16(f);
    return *reinterpret_cast<unsigned short*>(&b);
}

// buf element j of a row held as f32x4 vectors; j must be compile-time const
#define BG(buf, j) (buf[(j) >> 2][(j) & 3])

// ---------- weight preps + LayerNorm + ssm zeroing in ONE launch ----------
// W_x column remap so ssm rows are: col 0 = dt_raw, cols 4..19 = B, cols 20..35 = C.
__global__ void prep_all(const float* __restrict__ Win, const float* __restrict__ Wout,
                         const float* __restrict__ Wx, const float* __restrict__ x,
                         const float* __restrict__ lng, const float* __restrict__ lnb,
                         bf16* __restrict__ WinT, bf16* __restrict__ WoutT,
                         bf16* __restrict__ WxT, bf16* __restrict__ xn,
                         float* __restrict__ ssm) {
    __shared__ float t[32][33];
    int bid = blockIdx.x, tid = threadIdx.x;
    int tx = tid & 31, ty4 = (tid >> 5) * 4;
    if (bid < 4096) {               // W_in [1024][4096] -> WinT [4096][1024]
        int n0 = (bid & 127) * 32, k0 = (bid >> 7) * 32;
#pragma unroll
        for (int r = 0; r < 4; r++)
            t[ty4 + r][tx] = Win[(size_t)(k0 + ty4 + r) * 4096 + n0 + tx];
        __syncthreads();
#pragma unroll
        for (int r = 0; r < 4; r++)
            WinT[(size_t)(n0 + ty4 + r) * 1024 + k0 + tx] = __float2bfloat16(t[tx][ty4 + r]);
    } else if (bid < 6144) {        // W_out [2048][1024] -> WoutT [1024][2048]
        int b = bid - 4096;
        int n0 = (b & 31) * 32, k0 = (b >> 5) * 32;
#pragma unroll
        for (int r = 0; r < 4; r++)
            t[ty4 + r][tx] = Wout[(size_t)(k0 + ty4 + r) * 1024 + n0 + tx];
        __syncthreads();
#pragma unroll
        for (int r = 0; r < 4; r++)
            WoutT[(size_t)(n0 + ty4 + r) * 2048 + k0 + tx] = __float2bfloat16(t[tx][ty4 + r]);
    } else if (bid < 6656) {        // W_x [2048][33] -> WxT [64][2048], remapped + zero-pad
        int idx = (bid - 6144) * 256 + tid;
        int n = idx >> 11, k = idx & 2047;
        int j = (n == 0) ? 0 : (n >= 4 && n <= 35) ? n - 3 : -1;
        WxT[idx] = __float2bfloat16(j >= 0 ? Wx[k * 33 + j] : 0.f);
    } else if (bid < 8704) {        // LayerNorm row
        int row = bid - 6656;
        const float* xr = x + (size_t)row * DMODEL;
        float v[4];
        float s = 0.f, q = 0.f;
#pragma unroll
        for (int i = 0; i < 4; i++) {
            v[i] = xr[tid + i * 256];
            s += v[i];
            q += v[i] * v[i];
        }
        __shared__ float sh_s[256], sh_q[256];
        sh_s[tid] = s; sh_q[tid] = q;
        __syncthreads();
        for (int st = 128; st > 0; st >>= 1) {
            if (tid < st) { sh_s[tid] += sh_s[tid + st]; sh_q[tid] += sh_q[tid + st]; }
            __syncthreads();
        }
        float mean = sh_s[0] * (1.f / DMODEL);
        float var  = sh_q[0] * (1.f / DMODEL) - mean * mean;
        float rstd = rsqrtf(var + LN_EPS);
#pragma unroll
        for (int i = 0; i < 4; i++) {
            int c = tid + i * 256;
            xn[(size_t)row * DMODEL + c] =
                __float2bfloat16((v[i] - mean) * rstd * lng[c] + lnb[c]);
        }
    } else {                        // zero ssm (gemm2 accumulates atomically)
        int zi = (bid - 8704) * 256 + tid;
        if (zi < 32784)             // (2049 rows x 64) / 4 incl. padded tail row
            ((f32x4*)ssm)[zi] = f32x4{0.f, 0.f, 0.f, 0.f};
    }
}

// ---------- MFMA GEMM: C = A[M][lda](bf16) * Bt[N][lda](bf16)^T ----------
// OUT_MODE: 0 = f32 store (z-sliced), 1 = bf16 store, 2 = f32 atomicAdd.
// XCD_SWZ: bijective blockIdx remap so each XCD gets contiguous tiles.
template <int BM, int BN, int WAVE_M, int WAVE_N, int WRITE_RESID, int OUT_MODE,
          int XCD_SWZ>
__global__ void gemm_mfma(const bf16* __restrict__ A, const bf16* __restrict__ Bt,
                          void* __restrict__ Cv, const float* __restrict__ resid,
                          int M, int N, int Kslice, int lda) {
    constexpr int WMsz = BM / WAVE_M;
    constexpr int WNsz = BN / WAVE_N;
    constexpr int TM = WMsz / 16;
    constexpr int TN = WNsz / 16;
    __shared__ short As[BM * 64];
    __shared__ short Bs[BN * 64];
    int tid = threadIdx.x;
    int lane = tid & 63, wave = tid >> 6;
    int wm = (wave / WAVE_N) * WMsz, wn = (wave % WAVE_N) * WNsz;
    int wgx = blockIdx.x, wgy = blockIdx.y;
    if (XCD_SWZ) {                  // requires gridDim.x*gridDim.y % 8 == 0
        int nwg = gridDim.x * gridDim.y;
        int w = wgy * gridDim.x + wgx;
        int s = (w & 7) * (nwg >> 3) + (w >> 3);
        wgx = s % gridDim.x;
        wgy = s / gridDim.x;
    }
    int rowBase = wgy * BM, colBase = wgx * BN;
    int kbase = blockIdx.z * Kslice;

    f32x4 acc[TM][TN];
#pragma unroll
    for (int i = 0; i < TM; i++)
#pragma unroll
        for (int j = 0; j < TN; j++) acc[i][j] = f32x4{0.f, 0.f, 0.f, 0.f};

    int srow = tid >> 3;
    int cc = (tid & 7) ^ (srow & 7);
    const int ldsoff = tid * 16;

    for (int k0 = kbase; k0 < kbase + Kslice; k0 += 64) {
#pragma unroll
        for (int j = 0; j < BM / 32; j++)
            g2l16((char*)As + j * 4096 + ldsoff,
                  A + (size_t)(rowBase + j * 32 + srow) * lda + k0 + cc * 8);
#pragma unroll
        for (int j = 0; j < BN / 32; j++)
            g2l16((char*)Bs + j * 4096 + ldsoff,
                  Bt + (size_t)(colBase + j * 32 + srow) * lda + k0 + cc * 8);
        __syncthreads();
#pragma unroll
        for (int ks = 0; ks < 2; ks++) {
            bf16x8 af[TM], bfr[TN];
#pragma unroll
            for (int i = 0; i < TM; i++) {
                int row = wm + i * 16 + (lane & 15);
                int slot = (ks * 4 + (lane >> 4)) ^ (row & 7);
                af[i] = *(const bf16x8*)((const char*)As + row * 128 + slot * 16);
            }
#pragma unroll
            for (int j = 0; j < TN; j++) {
                int row = wn + j * 16 + (lane & 15);
                int slot = (ks * 4 + (lane >> 4)) ^ (row & 7);
                bfr[j] = *(const bf16x8*)((const char*)Bs + row * 128 + slot * 16);
            }
#pragma unroll
            for (int i = 0; i < TM; i++)
#pragma unroll
                for (int j = 0; j < TN; j++)
                    acc[i][j] = __builtin_amdgcn_mfma_f32_16x16x32_bf16(
                        af[i], bfr[j], acc[i][j], 0, 0, 0);
        }
        __syncthreads();
    }
    int rq = lane >> 4, cn = lane & 15;
    float* Cf = (float*)Cv + (size_t)blockIdx.z * M * N;
#pragma unroll
    for (int i = 0; i < TM; i++) {
#pragma unroll
        for (int j = 0; j < TN; j++) {
#pragma unroll
            for (int r = 0; r < 4; r++) {
                size_t row = rowBase + wm + i * 16 + rq * 4 + r;
                int col = colBase + wn + j * 16 + cn;
                float v = acc[i][j][r];
                if (WRITE_RESID) v += resid[row * N + col];
                if (OUT_MODE == 1)
                    ((bf16*)Cv)[row * N + col] = __float2bfloat16(v);
                else if (OUT_MODE == 2)
                    atomicAdd((float*)Cv + row * N + col, v);
                else
                    Cf[row * N + col] = v;
            }
        }
    }
}

// ---------- Causal depthwise conv(4) + SiLU, 4-wide over d ----------
__global__ void conv_silu(const bf16* __restrict__ xz, const float* __restrict__ cw,
                          const float* __restrict__ cb, bf16* __restrict__ xc) {
    int idx = blockIdx.x * 256 + threadIdx.x;   // T_LEN * DINNER/4 threads
    int t = idx >> 9, d4 = (idx & 511) * 4;
    const f32x4 bv = *(const f32x4*)(cb + d4);
    float acc0 = bv[0], acc1 = bv[1], acc2 = bv[2], acc3 = bv[3];
    const f32x4* cwv = (const f32x4*)(cw + d4 * 4);  // rows d4..d4+3
    f32x4 w0 = cwv[0], w1 = cwv[1], w2 = cwv[2], w3 = cwv[3];
#pragma unroll
    for (int k = 0; k < 4; k++) {
        int tt = t - 3 + k;
        if (tt >= 0) {
            ushort4 v = *(const ushort4*)((const short*)xz + (size_t)tt * (2 * DINNER) + d4);
            acc0 = fmaf(b2f((short)v.x), w0[k], acc0);
            acc1 = fmaf(b2f((short)v.y), w1[k], acc1);
            acc2 = fmaf(b2f((short)v.z), w2[k], acc2);
            acc3 = fmaf(b2f((short)v.w), w3[k], acc3);
        }
    }
    ushort4 o;
    o.x = f2bu(acc0 / (1.f + __expf(-acc0)));
    o.y = f2bu(acc1 / (1.f + __expf(-acc1)));
    o.z = f2bu(acc2 / (1.f + __expf(-acc2)));
    o.w = f2bu(acc3 / (1.f + __expf(-acc3)));
    *(ushort4*)((short*)xc + (size_t)t * DINNER + d4) = o;
}

__device__ __forceinline__ float softplus_f(float pre) {
    return (pre > 20.f) ? pre : log1pf(__expf(pre));
}

// q^1..q^16 in a[0..15], log-depth
__device__ __forceinline__ void powtree(float q, float* a) {
    a[0] = q;
    a[1] = q * q;
    a[2] = a[1] * q;
    a[3] = a[1] * a[1];
#pragma unroll
    for (int j = 0; j < 4; j++) a[4 + j] = a[j] * a[3];
#pragma unroll
    for (int j = 0; j < 8; j++) a[8 + j] = a[j] * a[7];
}

__device__ __forceinline__ void ldrow4(f32x4* b, const f32x4* sp) {
#pragma unroll
    for (int k = 0; k < 4; k++) b[k] = sp[k];
}

__device__ __forceinline__ void ldrow8(f32x4* b, const f32x4* sp) {
#pragma unroll
    for (int k = 0; k < 8; k++) b[k] = sp[k];
}

// ---------- Scan pass 1: TWO-PHASE ----------
// Phase A: bulk dt/q (16 independent softplus/exp chains), Lsum prefix, dq store.
// Phase B: scan loop = powtree + FMAs only.
__global__ void scan_pass1(
        const float* __restrict__ ssm, const bf16* __restrict__ xc,
        const float* __restrict__ Wdt, const float* __restrict__ bdt,
        const float* __restrict__ Alog,
        float* __restrict__ Ld, float* __restrict__ S, f32x2* __restrict__ dq) {
    int tid = threadIdx.x;
    int d = blockIdx.x * 256 + tid;
    int c = blockIdx.y;
    int t0 = c * CLEN;
    float A[DSTATE];
    bool fast = true;
#pragma unroll
    for (int n = 0; n < DSTATE; n++) {
        A[n] = -__expf(Alog[d * DSTATE + n]);
        fast = fast && (fabsf(A[n] + (float)(n + 1)) < 1e-3f * (n + 1));
    }
    float wdt = Wdt[d], bd = bdt[d];
    const float* srow = ssm + (size_t)t0 * SSTR;
    const short* xcp = (const short*)xc + (size_t)t0 * DINNER + d;

    // ---- phase A ----
    float dtv[CLEN], qv[CLEN];
#pragma unroll
    for (int i = 0; i < CLEN; i++)
        dtv[i] = softplus_f(srow[i * SSTR] * wdt + bd);   // uniform s_load, indep.
#pragma unroll
    for (int i = 0; i < CLEN; i++)
        qv[i] = __expf(-dtv[i]);                          // indep.
    short xcv[CLEN];
#pragma unroll
    for (int i = 0; i < CLEN; i++)
        xcv[i] = xcp[(size_t)i * DINNER];
    float Lsum = 0.f;
    f32x2* dqp = dq + (size_t)t0 * DINNER + d;
#pragma unroll
    for (int i = 0; i < CLEN; i++) {
        Lsum += dtv[i];
        dqp[(size_t)i * DINNER] = f32x2{dtv[i], qv[i]};
    }
    Ld[(size_t)c * DINNER + d] = Lsum;

    // ---- phase B ----
    float Sv[DSTATE];
#pragma unroll
    for (int n = 0; n < DSTATE; n++) Sv[n] = 0.f;
    if (fast) {
#pragma unroll
        for (int i = 0; i < CLEN; i++) {
            f32x4 bB[4];
            ldrow4(bB, (const f32x4*)(srow + i * SSTR + 4));   // cols 4..19 (B)
            float u = dtv[i] * b2f(xcv[i]);
            float a[DSTATE];
            powtree(qv[i], a);
#pragma unroll
            for (int n = 0; n < DSTATE; n++)
                Sv[n] = fmaf(a[n], Sv[n], u * bB[n >> 2][n & 3]);
        }
    } else {
#pragma unroll
        for (int i = 0; i < CLEN; i++) {
            f32x4 bB[4];
            ldrow4(bB, (const f32x4*)(srow + i * SSTR + 4));
            float u = dtv[i] * b2f(xcv[i]);
#pragma unroll
            for (int n = 0; n < DSTATE; n++)
                Sv[n] = fmaf(__expf(dtv[i] * A[n]), Sv[n], u * bB[n >> 2][n & 3]);
        }
    }
    size_t base = (size_t)c * DINNER * DSTATE + d;   // [c][n][d]
#pragma unroll
    for (int n = 0; n < DSTATE; n++)
        S[base + (size_t)n * DINNER] = Sv[n];
}

// ---------- Scan pass 2: block-segmented scan over chunks ----------
// grid (DINNER/64, DSTATE), 256 thr = 64 d x 4 segments of 32 chunks.
#define SEGL (NCHUNK / 4)
__global__ void scan_pass2(const float* __restrict__ Ld, const float* __restrict__ S,
                           const float* __restrict__ Alog, float* __restrict__ Hst) {
    int tx = threadIdx.x & 63, ty = threadIdx.x >> 6;
    int d = blockIdx.x * 64 + tx;
    int n = blockIdx.y;
    float A = -__expf(Alog[d * DSTATE + n]);
    int c0 = ty * SEGL;
    float lv[SEGL], sv[SEGL];
#pragma unroll
    for (int j = 0; j < SEGL; j++) {
        int cc = c0 + j;
        lv[j] = Ld[(size_t)cc * DINNER + d];
        sv[j] = S[(size_t)cc * DINNER * DSTATE + (size_t)n * DINNER + d];
    }
    float Lsum = 0.f, Sseg = 0.f;
#pragma unroll
    for (int j = 0; j < SEGL; j++) {
        Sseg = fmaf(__expf(A * lv[j]), Sseg, sv[j]);
        Lsum += lv[j];
    }
    __shared__ float shL[4][64], shS[4][64], shC[4][64];
    shL[ty][tx] = Lsum;
    shS[ty][tx] = Sseg;
    __syncthreads();
    if (ty == 0) {
        float car = 0.f;
        shC[0][tx] = 0.f;
#pragma unroll
        for (int s = 0; s < 3; s++) {
            car = fmaf(__expf(A * shL[s][tx]), car, shS[s][tx]);
            shC[s + 1][tx] = car;
        }
    }
    __syncthreads();
    float H = shC[ty][tx];
#pragma unroll
    for (int j = 0; j < SEGL; j++) {
        size_t o = (size_t)(c0 + j) * DINNER * DSTATE + (size_t)n * DINNER + d;
        Hst[o] = H;
        H = fmaf(__expf(A * lv[j]), H, sv[j]);
    }
}

// ---------- Scan pass 3 step + pipelined loop, fused epilogue ----------
// buf = 8 vecs: cols 4..35 of the ssm row => B at idx 0..15, C at idx 16..31.
// dt/q arrive precomputed from pass1 via dq (kills the softplus/exp chain).
template <int FAST>
__device__ __forceinline__ void p3_step(const f32x4* buf, f32x2 dq, short xcs, short zs,
                                        float Dd, const float* A,
                                        float* h, bf16* outp) {
    float dt = dq[0], q = dq[1];
    float xcf = b2f(xcs);
    float u = dt * xcf;
    float y;
    if (FAST) {
        float a[DSTATE];
        powtree(q, a);
        float y0 = 0.f, y1 = 0.f, y2 = 0.f, y3 = 0.f;
#pragma unroll
        for (int n = 0; n < 4; n++) {
            h[n]      = fmaf(a[n],      h[n],      u * BG(buf, n));
            y0 = fmaf(h[n],      BG(buf, 16 + n), y0);
            h[n + 4]  = fmaf(a[n + 4],  h[n + 4],  u * BG(buf, 4 + n));
            y1 = fmaf(h[n + 4],  BG(buf, 20 + n), y1);
            h[n + 8]  = fmaf(a[n + 8],  h[n + 8],  u * BG(buf, 8 + n));
            y2 = fmaf(h[n + 8],  BG(buf, 24 + n), y2);
            h[n + 12] = fmaf(a[n + 12], h[n + 12], u * BG(buf, 12 + n));
            y3 = fmaf(h[n + 12], BG(buf, 28 + n), y3);
        }
        y = (y0 + y1) + (y2 + y3);
    } else {
        y = 0.f;
#pragma unroll
        for (int n = 0; n < DSTATE; n++) {
            float a = __expf(dt * A[n]);
            h[n] = fmaf(a, h[n], u * BG(buf, n));
            y = fmaf(h[n], BG(buf, 16 + n), y);
        }
    }
    float z = b2f(zs);
    float sz = z / (1.f + __expf(-z));
    *outp = __float2bfloat16(fmaf(xcf, Dd, y) * sz);
}

template <int FAST>
__device__ __forceinline__ void p3_loop(const f32x4* sp8, const f32x2* dqp,
                                        const short* xcp, const short* zp,
                                        float Dd, const float* A,
                                        float* h, bf16* yp) {
    f32x4 bA[8], bB[8];
    f32x2 qA, qB;
    short xA, xB, zA, zB;
    ldrow8(bA, sp8);
    qA = dqp[0];
    xA = xcp[0];
    zA = zp[0];
#pragma unroll
    for (int i = 0; i < CLEN; i += 2) {
        ldrow8(bB, sp8 + (i + 1) * 16);
        qB = dqp[(size_t)(i + 1) * DINNER];
        xB = xcp[(size_t)(i + 1) * DINNER];
        zB = zp[(size_t)(i + 1) * 2 * DINNER];
        p3_step<FAST>(bA, qA, xA, zA, Dd, A, h, yp + (size_t)i * DINNER);
        ldrow8(bA, sp8 + (i + 2) * 16);
        qA = dqp[(size_t)(i + 2) * DINNER];
        xA = xcp[(size_t)(i + 2) * DINNER];
        zA = zp[(size_t)(i + 2) * 2 * DINNER];
        p3_step<FAST>(bB, qB, xB, zB, Dd, A, h, yp + (size_t)(i + 1) * DINNER);
    }
}

__global__ void scan_pass3(
        const float* __restrict__ ssm, const f32x2* __restrict__ dq,
        const bf16* __restrict__ xc, const bf16* __restrict__ xz,
        const float* __restrict__ Alog, const float* __restrict__ Dp,
        const float* __restrict__ Hst, bf16* __restrict__ yf) {
    int tid = threadIdx.x;
    int d = blockIdx.x * 256 + tid;
    int c = blockIdx.y;
    int t0 = c * CLEN;
    float A[DSTATE], h[DSTATE];
    bool fast = true;
    size_t base = (size_t)c * DINNER * DSTATE + d;
#pragma unroll
    for (int n = 0; n < DSTATE; n++) {
        A[n] = -__expf(Alog[d * DSTATE + n]);
        fast = fast && (fabsf(A[n] + (float)(n + 1)) < 1e-3f * (n + 1));
        h[n] = Hst[base + (size_t)n * DINNER];
    }
    float Dd = Dp[d];
    const f32x4* sp8 = (const f32x4*)(ssm + (size_t)t0 * SSTR) + 1;
    const f32x2* dqp = dq + (size_t)t0 * DINNER + d;
    const short* xcp = (const short*)xc + (size_t)t0 * DINNER + d;
    const short* zp  = (const short*)xz + (size_t)t0 * (2 * DINNER) + DINNER + d;
    bf16* yp = yf + (size_t)t0 * DINNER + d;
    if (fast)
        p3_loop<1>(sp8, dqp, xcp, zp, Dd, A, h, yp);
    else
        p3_loop<0>(sp8, dqp, xcp, zp, Dd, A, h, yp);
}

extern "C" void kernel_launch(void* const* d_in, const int* in_sizes, int n_in,
                              void* d_out, int out_size, void* d_ws, size_t ws_size,
                              hipStream_t stream) {
    const float* x     = (const float*)d_in[0];
    const float* W_in  = (const float*)d_in[1];
    const float* convw = (const float*)d_in[2];
    const float* convb = (const float*)d_in[3];
    const float* W_x   = (const float*)d_in[4];
    const float* W_dt  = (const float*)d_in[5];
    const float* b_dt  = (const float*)d_in[6];
    const float* A_log = (const float*)d_in[7];
    const float* Dp    = (const float*)d_in[8];
    const float* W_out = (const float*)d_in[9];
    const float* ln_g  = (const float*)d_in[10];
    const float* ln_b  = (const float*)d_in[11];
    float* out = (float*)d_out;

    // ~118 MB of the 256 MiB workspace; no aliasing. ssm has a padded tail row
    // (pass3 prefetch reads one row past the end); dq tail prefetch stays
    // in-workspace.
    char* wsb = (char*)d_ws;
    bf16*  xn    = (bf16*)(wsb);                    //  4 MB
    bf16*  WinT  = (bf16*)(wsb + (4ull  << 20));    //  8 MB
    bf16*  WoutT = (bf16*)(wsb + (12ull << 20));    //  4 MB
    bf16*  WxT   = (bf16*)(wsb + (16ull << 20));    //  0.25 MB
    bf16*  xz    = (bf16*)(wsb + (17ull << 20));    // 16 MB
    bf16*  xc    = (bf16*)(wsb + (33ull << 20));    //  8 MB
    float* Ld    = (float*)(wsb + (43ull << 20));   //  1 MB (128 x 2048)
    float* Hst   = (float*)(wsb + (44ull << 20));   // 16 MB
    float* S     = (float*)(wsb + (60ull << 20));   // 16 MB
    bf16*  yf    = (bf16*)(wsb + (76ull << 20));    //  8 MB
    float* ssm   = (float*)(wsb + (84ull << 20));   //  0.5 MB + pad
    f32x2* dq    = (f32x2*)(wsb + (86ull << 20));   // 32 MB (2048 x 2048 x float2)

    prep_all<<<8833, 256, 0, stream>>>(W_in, W_out, W_x, x, ln_g, ln_b,
                                       WinT, WoutT, WxT, xn, ssm);

    gemm_mfma<128, 128, 2, 2, 0, 1, 1><<<dim3(4096 / 128, 2048 / 128), 256, 0, stream>>>(
        xn, WinT, xz, nullptr, 2048, 4096, 1024, 1024);

    conv_silu<<<(T_LEN * DINNER / 4) / 256, 256, 0, stream>>>(xz, convw, convb, xc);

    // split-K=4, partials summed directly into ssm via f32 atomics
    gemm_mfma<32, 64, 2, 2, 0, 2, 0><<<dim3(1, 2048 / 32, 4), 256, 0, stream>>>(
        xc, WxT, ssm, nullptr, 2048, 64, 512, 2048);

    scan_pass1<<<dim3(DINNER / 256, NCHUNK), 256, 0, stream>>>(
        ssm, xc, W_dt, b_dt, A_log, Ld, S, dq);
    scan_pass2<<<dim3(DINNER / 64, DSTATE), 256, 0, stream>>>(Ld, S, A_log, Hst);
    scan_pass3<<<dim3(DINNER / 256, NCHUNK), 256, 0, stream>>>(
        ssm, dq, xc, xz, A_log, Dp, Hst, yf);

    gemm_mfma<64, 64, 2, 2, 1, 0, 1><<<dim3(1024 / 64, 2048 / 64), 256, 0, stream>>>(
        yf, WoutT, out, x, 2048, 1024, 2048, 2048);
}